// Round 7
// baseline (277.148 us; speedup 1.0000x reference)
//
#include <hip/hip_runtime.h>

#define B_    4
#define C_    256
#define H_    64
#define W_    64
#define HW_   4096
#define NG_   32
#define CPG_  8
#define KK_   9
#define NOFF_ 18

typedef __attribute__((ext_vector_type(8))) short short8;
typedef __attribute__((ext_vector_type(4))) short short4v;
typedef __attribute__((ext_vector_type(4))) float floatx4;
typedef __attribute__((ext_vector_type(16))) float floatx16;

static __device__ __forceinline__ short f2bf(float f) {
    union { float f; unsigned u; } v; v.f = f;
    unsigned r = v.u + 0x7fff + ((v.u >> 16) & 1);   // RNE
    return (short)(r >> 16);
}
static __device__ __forceinline__ float bf2f(short s) {
    union { unsigned u; float f; } v;
    v.u = ((unsigned)(unsigned short)s) << 16;
    return v.f;
}
// packed f32x2 -> bf16x2 (RNE), single VALU op
static __device__ __forceinline__ unsigned pkbf(float lo, float hi) {
    unsigned r;
    asm("v_cvt_pk_bf16_f32 %0, %1, %2" : "=v"(r) : "v"(lo), "v"(hi));
    return r;
}

// ---------------------------------------------------------------------------
// K1: GroupNorm (32 groups) + ReLU -> bf16 [C][HW]. fp32-input variant.
// ---------------------------------------------------------------------------
__global__ __launch_bounds__(1024) void gn_relu_f32_kernel(
    const float* __restrict__ in, const float* __restrict__ gamma,
    const float* __restrict__ beta, short* __restrict__ outb)
{
    int b = blockIdx.x >> 5;
    int g = blockIdx.x & 31;
    const int N = CPG_ * HW_;              // 32768
    size_t base = ((size_t)(b * C_ + g * CPG_)) * HW_;
    const float4* in4 = (const float4*)(in + base);
    int t = threadIdx.x;

    float s = 0.f, ss = 0.f;
    for (int i = t; i < N / 4; i += 1024) {
        float4 v = in4[i];
        s  += v.x + v.y + v.z + v.w;
        ss += v.x * v.x + v.y * v.y + v.z * v.z + v.w * v.w;
    }
    #pragma unroll
    for (int off = 32; off > 0; off >>= 1) {
        s  += __shfl_down(s, off, 64);
        ss += __shfl_down(ss, off, 64);
    }
    __shared__ float red[32];
    __shared__ float sh_rs, sh_m;
    int wid = t >> 6;
    if ((t & 63) == 0) { red[wid] = s; red[16 + wid] = ss; }
    __syncthreads();
    if (t == 0) {
        float S = 0.f, SS = 0.f;
        #pragma unroll
        for (int i = 0; i < 16; ++i) { S += red[i]; SS += red[16 + i]; }
        float m = S / (float)N;
        float var = SS / (float)N - m * m;
        sh_rs = rsqrtf(var + 1e-5f);
        sh_m = m;
    }
    __syncthreads();
    float rs = sh_rs, m = sh_m;
    short4v* out4 = (short4v*)(outb + base);
    for (int i = t; i < N / 4; i += 1024) {
        int ch = g * CPG_ + (i >> 10);
        float ga = gamma[ch] * rs;
        float be = beta[ch] - m * ga;
        float4 v = in4[i];
        short4v o;
        o.x = f2bf(fmaxf(fmaf(v.x, ga, be), 0.f));
        o.y = f2bf(fmaxf(fmaf(v.y, ga, be), 0.f));
        o.z = f2bf(fmaxf(fmaf(v.z, ga, be), 0.f));
        o.w = f2bf(fmaxf(fmaf(v.w, ga, be), 0.f));
        out4[i] = o;
    }
}

// bf16-input variant (reads layer-1 output y1 in bf16)
__global__ __launch_bounds__(1024) void gn_relu_bf16_kernel(
    const short* __restrict__ in, const float* __restrict__ gamma,
    const float* __restrict__ beta, short* __restrict__ outb)
{
    int b = blockIdx.x >> 5;
    int g = blockIdx.x & 31;
    const int N = CPG_ * HW_;
    size_t base = ((size_t)(b * C_ + g * CPG_)) * HW_;
    const short4v* in4 = (const short4v*)(in + base);
    int t = threadIdx.x;

    float s = 0.f, ss = 0.f;
    for (int i = t; i < N / 4; i += 1024) {
        short4v sv = in4[i];
        float vx = bf2f(sv.x), vy = bf2f(sv.y), vz = bf2f(sv.z), vw = bf2f(sv.w);
        s  += vx + vy + vz + vw;
        ss += vx * vx + vy * vy + vz * vz + vw * vw;
    }
    #pragma unroll
    for (int off = 32; off > 0; off >>= 1) {
        s  += __shfl_down(s, off, 64);
        ss += __shfl_down(ss, off, 64);
    }
    __shared__ float red[32];
    __shared__ float sh_rs, sh_m;
    int wid = t >> 6;
    if ((t & 63) == 0) { red[wid] = s; red[16 + wid] = ss; }
    __syncthreads();
    if (t == 0) {
        float S = 0.f, SS = 0.f;
        #pragma unroll
        for (int i = 0; i < 16; ++i) { S += red[i]; SS += red[16 + i]; }
        float m = S / (float)N;
        float var = SS / (float)N - m * m;
        sh_rs = rsqrtf(var + 1e-5f);
        sh_m = m;
    }
    __syncthreads();
    float rs = sh_rs, m = sh_m;
    short4v* out4 = (short4v*)(outb + base);
    for (int i = t; i < N / 4; i += 1024) {
        int ch = g * CPG_ + (i >> 10);
        float ga = gamma[ch] * rs;
        float be = beta[ch] - m * ga;
        short4v sv = in4[i];
        short4v o;
        o.x = f2bf(fmaxf(fmaf(bf2f(sv.x), ga, be), 0.f));
        o.y = f2bf(fmaxf(fmaf(bf2f(sv.y), ga, be), 0.f));
        o.z = f2bf(fmaxf(fmaf(bf2f(sv.z), ga, be), 0.f));
        o.w = f2bf(fmaxf(fmaf(bf2f(sv.w), ga, be), 0.f));
        out4[i] = o;
    }
}

// ---------------------------------------------------------------------------
// K2: fused {depthwise 7x7 -> fdwt octet-major} AND {transpose hbf -> ht
// [B][HW][C]}. Blocks 0..255: dw7t. Blocks 256..511: trA (XCD-swizzled).
// ---------------------------------------------------------------------------
__global__ __launch_bounds__(256) void dw7t_tr_kernel(
    const short* __restrict__ in,   // hbf [B][C][HW]
    const float* __restrict__ dwk,  // [C][49]
    short* __restrict__ fdwt,       // [B][64][32][64][8]
    short* __restrict__ ht)         // [B][HW][C]
{
    __shared__ __align__(16) char smem[78112];
    int t = threadIdx.x;
    int blk = blockIdx.x;
    if (blk < 256) {
        short (*tile)[38][72] = (short(*)[38][72])smem;          // 43776 B
        float (*wk8)[49]      = (float(*)[49])(smem + 43776);    // 1568 B
        short (*outs)[2048]   = (short(*)[2048])(smem + 45344);  // 32768 B
        int b = blk >> 6, o8 = (blk >> 1) & 31, rh = blk & 1;
        int c0 = o8 * 8;
        unsigned* tz = (unsigned*)smem;
        for (int i = t; i < 10944; i += 256) tz[i] = 0u;         // zero tile
        for (int i = t; i < 392; i += 256)
            wk8[i / 49][i % 49] = dwk[(c0 + i / 49) * 49 + (i % 49)];
        __syncthreads();
        // load 8 planes, rows rh*32-3 .. rh*32+34 (halo), cols at +4 pad
        for (int ch = 0; ch < 8; ++ch) {
            const short* src = in + ((size_t)(b * C_ + c0 + ch)) * HW_;
            for (int i = t; i < 608; i += 256) {
                int rr = i >> 4, xq = i & 15;
                int ry = rh * 32 + rr - 3;
                if (ry >= 0 && ry < 64) {
                    short4v v = *(const short4v*)(src + ry * 64 + xq * 4);
                    *(short4v*)&tile[ch][rr][4 + xq * 4] = v;
                }
            }
        }
        __syncthreads();
        // compute: 4096 quads (ch,y,x0)
        for (int it = 0; it < 16; ++it) {
            int q = it * 256 + t;
            int ch = q >> 9, y = (q >> 4) & 31, x0 = (q & 15) << 2;
            float a0 = 0.f, a1 = 0.f, a2 = 0.f, a3 = 0.f;
            const float* wr0 = wk8[ch];
            #pragma unroll
            for (int dy = 0; dy < 7; ++dy) {
                const short* trw = &tile[ch][y + dy][x0];
                short4v s0 = *(const short4v*)trw;
                short4v s1 = *(const short4v*)(trw + 4);
                short4v s2 = *(const short4v*)(trw + 8);
                float r[12] = {bf2f(s0.x), bf2f(s0.y), bf2f(s0.z), bf2f(s0.w),
                               bf2f(s1.x), bf2f(s1.y), bf2f(s1.z), bf2f(s1.w),
                               bf2f(s2.x), bf2f(s2.y), bf2f(s2.z), bf2f(s2.w)};
                const float* wr = wr0 + dy * 7;
                #pragma unroll
                for (int dx = 0; dx < 7; ++dx) {
                    float wv = wr[dx];
                    a0 = fmaf(r[dx + 1], wv, a0);
                    a1 = fmaf(r[dx + 2], wv, a1);
                    a2 = fmaf(r[dx + 3], wv, a2);
                    a3 = fmaf(r[dx + 4], wv, a3);
                }
            }
            short4v o;
            o.x = f2bf(a0); o.y = f2bf(a1); o.z = f2bf(a2); o.w = f2bf(a3);
            *(short4v*)&outs[ch][y * 64 + x0] = o;
        }
        __syncthreads();
        // octet-major coalesced write: 2048 px-chunks of 16B
        for (int it = 0; it < 8; ++it) {
            int p = it * 256 + t;
            short8 v;
            #pragma unroll
            for (int ch = 0; ch < 8; ++ch) v[ch] = outs[ch][p];
            *(short8*)(fdwt + (((size_t)(b * 64 + rh * 32 + (p >> 6)) * 32 + o8) * 64
                               + (p & 63)) * 8) = v;
        }
    } else {
        unsigned* ltile = (unsigned*)smem;     // 64*132 words = 33792 B
        int q0 = blk - 256;
        int q = ((q0 & 7) << 5) | (q0 >> 3);   // XCD swizzle (matches deform)
        int b = q >> 6;
        int px0 = (q & 63) * 64;
        const short* sb = in + (size_t)b * C_ * HW_;
        int pq4 = t & 15, cphi = t >> 4;
        #pragma unroll
        for (int i = 0; i < 8; ++i) {
            int cp = i * 16 + cphi;            // channel pair 0..127
            const short* r0 = sb + (size_t)(2 * cp) * HW_ + px0 + pq4 * 4;
            short4v lo = *(const short4v*)r0;
            short4v hi = *(const short4v*)(r0 + HW_);
            #pragma unroll
            for (int j = 0; j < 4; ++j) {
                int pl = pq4 * 4 + j;
                unsigned wrd = (unsigned)(unsigned short)lo[j]
                             | ((unsigned)(unsigned short)hi[j] << 16);
                ltile[pl * 132 + (cp ^ ((pl & 7) << 2))] = wrd;
            }
        }
        __syncthreads();
        int co = t & 31, ph2 = t >> 5;
        #pragma unroll
        for (int r = 0; r < 8; ++r) {
            int pl = r * 8 + ph2;
            uint4 v = *(const uint4*)&ltile[pl * 132 + ((co * 4) ^ ((pl & 7) << 2))];
            *(uint4*)(ht + ((size_t)b * HW_ + px0 + pl) * C_ + co * 8) = v;
        }
    }
}

// ---------------------------------------------------------------------------
// K3: pack weights. Blocks 0..4607: w1/w2 -> 32x32x16 A-fragment-major bf16.
// Blocks 4608..4671: pw1/pw2 -> 16x16x32 A-frags padded to 32 rows.
// ---------------------------------------------------------------------------
__global__ __launch_bounds__(256) void wpack_all_kernel(
    const float* __restrict__ w1, const float* __restrict__ w2,
    const float* __restrict__ pw1, const float* __restrict__ pw2,
    short* __restrict__ wp1, short* __restrict__ wp2,
    short* __restrict__ ppk1, short* __restrict__ ppk2)
{
    int blk = blockIdx.x;
    if (blk < 4608) {
        const float* w = (blk < 2304) ? w1 : w2;
        short* wp = (blk < 2304) ? wp1 : wp2;
        int idx = (blk % 2304) * 256 + threadIdx.x;
        int j    = idx & 7;
        int lane = (idx >> 3) & 63;
        int ot   = (idx >> 9) & 7;                   // o-tile 0..7 (32 rows)
        int slab = idx >> 12;                        // 0..143 = g*16 + cc16
        int g = slab >> 4, cc16 = slab & 15;
        int o = ot * 32 + (lane & 31);
        int c = cc16 * 16 + (lane >> 5) * 8 + j;
        wp[idx] = f2bf(w[(size_t)(o * C_ + c) * KK_ + g]);
    } else {
        int q = blk - 4608;                          // 0..63
        const float* pw = (q < 32) ? pw1 : pw2;
        short* ppk = (q < 32) ? ppk1 : ppk2;
        int idx = (q & 31) * 256 + threadIdx.x;      // 0..8191
        int j = idx & 7, lane = (idx >> 3) & 63;
        int ot = (idx >> 9) & 1, sl = idx >> 10;     // 0..7
        int o = ot * 16 + (lane & 15);
        int k = sl * 32 + (lane >> 4) * 8 + j;
        ppk[idx] = (o < NOFF_) ? f2bf(pw[o * C_ + k]) : (short)0;
    }
}

// ---------------------------------------------------------------------------
// K4: fused deformable layer. One block (1024 thr = 16 waves) per (b,row),
// XCD-swizzled. Round-7 retile: LDS B-read amplification was the measured
// bottleneck (512 x ds_read_b128 = 512KB/tap vs 256KB L2 streams). Waves are
// now (o-pair oq 0..3) x (K-quarter kq 0..3): each wave computes 2 o-tiles x
// 2 px-tiles x 4 slabs -> each B-fragment read feeds 2 MFMAs (B-reads
// halved, 256/tap), A-fragments still read exactly once block-wide.
// One-time 3-phase LDS K-combine replaces the old pairwise exchange.
// ---------------------------------------------------------------------------
__global__ __launch_bounds__(1024, 4) void deform_fused_kernel(
    const short* __restrict__ ht,   const short* __restrict__ fdw,
    const short* __restrict__ ppk,  const float* __restrict__ pwb,
    const short* __restrict__ wp,   const float* __restrict__ bias,
    const float* __restrict__ resid, float* __restrict__ outf,
    short* __restrict__ outb)
{
    int lb = ((blockIdx.x & 7) << 5) | (blockIdx.x >> 3);   // XCD swizzle
    int b = lb >> 6;
    int row = lb & 63;
    __shared__ int   i00[576], i01[576], i10[576], i11[576];
    __shared__ float c00[576], c01[576], c10[576], c11[576];
    __shared__ __align__(16) short sbuf[2][16384];    // 2 x 32KB: [64px][256ch]
    float* off_lds = (float*)&sbuf[0][0];             // 18*64 floats, dead later
    int t = threadIdx.x;
    int wv = t >> 6, lane = t & 63;
    int pq = lane >> 4, pr = lane & 15;
    int l31 = lane & 31, hi = lane >> 5;

    // ---- stage A: pw offsets via 16x16x32 MFMA (waves 0..7, full C) ----
    if (wv < 8) {
        int ot = wv & 1, ptw = wv >> 1;
        int px = ptw * 16 + pr;
        const short8* fdw8 = (const short8*)fdw;
        size_t fbase = ((size_t)(b * 64 + row)) * 32;
        const short8* ap = (const short8*)ppk;
        floatx4 pacc = (floatx4){0.f, 0.f, 0.f, 0.f};
        #pragma unroll
        for (int sl = 0; sl < 8; ++sl) {
            short8 af = ap[(sl * 2 + ot) * 64 + lane];
            short8 bf = fdw8[(fbase + sl * 4 + pq) * 64 + px];
            pacc = __builtin_amdgcn_mfma_f32_16x16x32_bf16(af, bf, pacc, 0, 0, 0);
        }
        #pragma unroll
        for (int r = 0; r < 4; ++r) {
            int o = ot * 16 + pq * 4 + r;
            if (o < NOFF_) off_lds[o * 64 + px] = pacc[r] + pwb[o];
        }
    }
    __syncthreads();

    // ---- stage B: bilinear coefficient tables ----
    if (t < 576) {
        int e = t;
        int k = e >> 6, p = e & 63;
        float offy = off_lds[(2 * k) * 64 + p];
        float offx = off_lds[(2 * k + 1) * 64 + p];
        float py = (float)row + (float)(k / 3 - 1) + offy;
        float px = (float)p   + (float)(k % 3 - 1) + offx;
        float y0f = floorf(py), x0f = floorf(px);
        float wy1 = py - y0f, wx1 = px - x0f;
        float wy0 = 1.f - wy1, wx0 = 1.f - wx1;
        float y1f = y0f + 1.f, x1f = x0f + 1.f;
        bool vy0 = (y0f >= 0.f) && (y0f <= 63.f);
        bool vy1 = (y1f >= 0.f) && (y1f <= 63.f);
        bool vx0 = (x0f >= 0.f) && (x0f <= 63.f);
        bool vx1 = (x1f >= 0.f) && (x1f <= 63.f);
        int iy0 = (int)fminf(fmaxf(y0f, 0.f), 63.f);
        int iy1 = (int)fminf(fmaxf(y1f, 0.f), 63.f);
        int ix0 = (int)fminf(fmaxf(x0f, 0.f), 63.f);
        int ix1 = (int)fminf(fmaxf(x1f, 0.f), 63.f);
        i00[e] = iy0 * 64 + ix0; i01[e] = iy0 * 64 + ix1;
        i10[e] = iy1 * 64 + ix0; i11[e] = iy1 * 64 + ix1;
        c00[e] = (vy0 && vx0) ? wy0 * wx0 : 0.f;
        c01[e] = (vy0 && vx1) ? wy0 * wx1 : 0.f;
        c10[e] = (vy1 && vx0) ? wy1 * wx0 : 0.f;
        c11[e] = (vy1 && vx1) ? wy1 * wx1 : 0.f;
    }
    __syncthreads();

    // ---- stage C setup (gather map identical to round 3) ----
    int c8a = t & 7;
    int pan = (t >> 3) & 1;
    int spx = t >> 4;                       // 0..63
    const short* hb0 = ht + ((size_t)b * HW_) * C_ + pan * 128 + c8a * 8;
    const short* hb1 = hb0 + 64;
    int oct0 = pan * 16 + c8a;              // staged octet ids 0..31
    int oct1 = oct0 + 8;
    // LDS: [64px][256ch] shorts; slot(oct,px) = (oct&16)|((oct^px)&15)
    int slotA = ((oct0 & 16) | ((oct0 ^ spx) & 15)) * 8;
    int slotB = ((oct1 & 16) | ((oct1 ^ spx) & 15)) * 8;
    int srow = spx * 256;

    short8 ra[4], rb[4];
    auto prefetch = [&](int g) {
        int e = g * 64 + spx;
        int a00 = i00[e], a01 = i01[e], a10 = i10[e], a11 = i11[e];
        ra[0] = *(const short8*)(hb0 + (size_t)a00 * C_);
        ra[1] = *(const short8*)(hb0 + (size_t)a01 * C_);
        ra[2] = *(const short8*)(hb0 + (size_t)a10 * C_);
        ra[3] = *(const short8*)(hb0 + (size_t)a11 * C_);
        rb[0] = *(const short8*)(hb1 + (size_t)a00 * C_);
        rb[1] = *(const short8*)(hb1 + (size_t)a01 * C_);
        rb[2] = *(const short8*)(hb1 + (size_t)a10 * C_);
        rb[3] = *(const short8*)(hb1 + (size_t)a11 * C_);
    };
    auto stage_write = [&](int g, int bi) {
        int e = g * 64 + spx;
        float w00 = c00[e], w01 = c01[e], w10 = c10[e], w11 = c11[e];
        uint4 va, vb;
        float f0, f1;
        #define BLEND(R, J) (w00 * bf2f(R[0][J]) + w01 * bf2f(R[1][J]) \
                           + w10 * bf2f(R[2][J]) + w11 * bf2f(R[3][J]))
        f0 = BLEND(ra, 0); f1 = BLEND(ra, 1); va.x = pkbf(f0, f1);
        f0 = BLEND(ra, 2); f1 = BLEND(ra, 3); va.y = pkbf(f0, f1);
        f0 = BLEND(ra, 4); f1 = BLEND(ra, 5); va.z = pkbf(f0, f1);
        f0 = BLEND(ra, 6); f1 = BLEND(ra, 7); va.w = pkbf(f0, f1);
        f0 = BLEND(rb, 0); f1 = BLEND(rb, 1); vb.x = pkbf(f0, f1);
        f0 = BLEND(rb, 2); f1 = BLEND(rb, 3); vb.y = pkbf(f0, f1);
        f0 = BLEND(rb, 4); f1 = BLEND(rb, 5); vb.z = pkbf(f0, f1);
        f0 = BLEND(rb, 6); f1 = BLEND(rb, 7); vb.w = pkbf(f0, f1);
        #undef BLEND
        short* sp = &sbuf[bi][srow];
        *(uint4*)&sp[slotA] = va;
        *(uint4*)&sp[slotB] = vb;
    };

    // wave roles: oq = o-pair (o-tiles 2oq, 2oq+1), kq = K-quarter (4 slabs)
    int oq = wv & 3;
    int kq = wv >> 2;

    floatx16 acc[2][2];   // [oi][pxt] -- all indices compile-time below
    #pragma unroll
    for (int i = 0; i < 16; ++i) {
        acc[0][0][i] = 0.f; acc[0][1][i] = 0.f;
        acc[1][0][i] = 0.f; acc[1][1][i] = 0.f;
    }

    prefetch(0);
    stage_write(0, 0);
    prefetch(1);
    __syncthreads();

    const short8* wp8 = (const short8*)wp;

    for (int g = 0; g < 9; ++g) {
        const short* sb = &sbuf[g & 1][0];
        #pragma unroll
        for (int s4 = 0; s4 < 4; ++s4) {
            int slab = kq * 4 + s4;                      // 0..15
            short8 a0 = wp8[(size_t)(((g * 16 + slab) * 8 + 2 * oq) * 64 + lane)];
            short8 a1 = wp8[(size_t)(((g * 16 + slab) * 8 + 2 * oq + 1) * 64 + lane)];
            int oct = slab * 2 + hi;
            int so = ((oct & 16) | ((oct ^ l31) & 15)) << 3;
            short8 b0 = *(const short8*)&sb[l31 * 256 + so];
            short8 b1 = *(const short8*)&sb[(32 + l31) * 256 + so];
            acc[0][0] = __builtin_amdgcn_mfma_f32_32x32x16_bf16(a0, b0, acc[0][0], 0, 0, 0);
            acc[0][1] = __builtin_amdgcn_mfma_f32_32x32x16_bf16(a0, b1, acc[0][1], 0, 0, 0);
            acc[1][0] = __builtin_amdgcn_mfma_f32_32x32x16_bf16(a1, b0, acc[1][0], 0, 0, 0);
            acc[1][1] = __builtin_amdgcn_mfma_f32_32x32x16_bf16(a1, b1, acc[1][1], 0, 0, 0);
        }
        if (g + 1 < 9) {
            stage_write(g + 1, (g + 1) & 1);
            if (g + 2 < 9) prefetch(g + 2);
        }
        __syncthreads();
    }

    // ---- K-combine: sum 4 K-quarters per (oq). 3 phases, 4 regions x 16KB.
    float* xf = (float*)&sbuf[0][0];          // 16384 floats = 64KB
    auto wr4 = [&](int reg) {
        float* bp = xf + reg * 4096;
        #pragma unroll
        for (int a = 0; a < 4; ++a) {
            #pragma unroll
            for (int q = 0; q < 4; ++q) {
                floatx4 v = {acc[a >> 1][a & 1][q * 4 + 0], acc[a >> 1][a & 1][q * 4 + 1],
                             acc[a >> 1][a & 1][q * 4 + 2], acc[a >> 1][a & 1][q * 4 + 3]};
                *(floatx4*)&bp[a * 1024 + q * 256 + lane * 4] = v;
            }
        }
    };
    auto rd4 = [&](int reg) {
        float* bp = xf + reg * 4096;
        #pragma unroll
        for (int a = 0; a < 4; ++a) {
            #pragma unroll
            for (int q = 0; q < 4; ++q) {
                floatx4 v = *(const floatx4*)&bp[a * 1024 + q * 256 + lane * 4];
                acc[a >> 1][a & 1][q * 4 + 0] += v.x;
                acc[a >> 1][a & 1][q * 4 + 1] += v.y;
                acc[a >> 1][a & 1][q * 4 + 2] += v.z;
                acc[a >> 1][a & 1][q * 4 + 3] += v.w;
            }
        }
    };
    if (kq == 1) wr4(oq);
    __syncthreads();
    if (kq == 0) rd4(oq);
    __syncthreads();
    if (kq == 3) wr4(oq);
    __syncthreads();
    if (kq == 2) rd4(oq);
    __syncthreads();
    if (kq == 2) wr4(oq);
    __syncthreads();
    if (kq == 0) rd4(oq);

    // ---- epilogue (kq==0 waves): 2 o-tiles x 2 px-tiles each ----
    // C/D 32x32: col = lane&31 (px), row = (r&3) + 8*(r>>2) + 4*hi (o)
    if (kq == 0) {
        #pragma unroll
        for (int oi = 0; oi < 2; ++oi) {
            #pragma unroll
            for (int r = 0; r < 16; ++r) {
                int o = oq * 64 + oi * 32 + (r & 3) + 8 * (r >> 2) + 4 * hi;
                float bo = bias[o];
                float v0 = acc[oi][0][r] + bo;
                float v1 = acc[oi][1][r] + bo;
                size_t ob = ((size_t)(b * C_ + o)) * HW_ + row * 64 + l31;
                if (outf) {
                    if (resid) { v0 += resid[ob]; v1 += resid[ob + 32]; }
                    outf[ob] = v0;
                    outf[ob + 32] = v1;
                } else {
                    outb[ob] = f2bf(v0);
                    outb[ob + 32] = f2bf(v1);
                }
            }
        }
    }
}

// ---------------------------------------------------------------------------
extern "C" void kernel_launch(void* const* d_in, const int* in_sizes, int n_in,
                              void* d_out, int out_size, void* d_ws, size_t ws_size,
                              hipStream_t stream)
{
    const float* x     = (const float*)d_in[0];
    const float* gn1_g = (const float*)d_in[1];
    const float* gn1_b = (const float*)d_in[2];
    const float* dw1   = (const float*)d_in[3];
    const float* pw1   = (const float*)d_in[4];
    const float* pwb1  = (const float*)d_in[5];
    const float* w1    = (const float*)d_in[6];
    const float* b1    = (const float*)d_in[7];
    const float* gn2_g = (const float*)d_in[8];
    const float* gn2_b = (const float*)d_in[9];
    const float* dw2   = (const float*)d_in[10];
    const float* pw2   = (const float*)d_in[11];
    const float* pwb2  = (const float*)d_in[12];
    const float* w2    = (const float*)d_in[13];
    const float* b2    = (const float*)d_in[14];
    float* out = (float*)d_out;

    float* ws   = (float*)d_ws;
    short* y1b  = (short*)ws;                  // bf16 [B][C][HW]       (8 MB)
    short* hbf  = (short*)(ws + 2097152);      // bf16 [B][C][HW]       (8 MB)
    short* hbt  = (short*)(ws + 4194304);      // bf16 [B][HW][C]       (8 MB)
    short* fdwt = (short*)(ws + 8388608);      // bf16 [B][64][32][64][8] (8 MB)
    short* wp1  = (short*)(ws + 10485760);     // 589,824 bf16
    short* wp2  = (short*)(ws + 10780672);     // 589,824 bf16
    short* ppk1 = (short*)(ws + 11075584);     // 8,192 bf16
    short* ppk2 = (short*)(ws + 11079680);     // 8,192 bf16

    wpack_all_kernel<<<4672, 256, 0, stream>>>(w1, w2, pw1, pw2,
                                               wp1, wp2, ppk1, ppk2);

    // layer 1
    gn_relu_f32_kernel<<<B_ * NG_, 1024, 0, stream>>>(x, gn1_g, gn1_b, hbf);
    dw7t_tr_kernel<<<512, 256, 0, stream>>>(hbf, dw1, fdwt, hbt);
    deform_fused_kernel<<<B_ * H_, 1024, 0, stream>>>(
        hbt, fdwt, ppk1, pwb1, wp1, b1, nullptr, nullptr, y1b);

    // layer 2 (+ residual x)
    gn_relu_bf16_kernel<<<B_ * NG_, 1024, 0, stream>>>(y1b, gn2_g, gn2_b, hbf);
    dw7t_tr_kernel<<<512, 256, 0, stream>>>(hbf, dw2, fdwt, hbt);
    deform_fused_kernel<<<B_ * H_, 1024, 0, stream>>>(
        hbt, fdwt, ppk2, pwb2, wp2, b2, x, out, nullptr);
}

// Round 8
// 269.640 us; speedup vs baseline: 1.0278x; 1.0278x over previous
//
#include <hip/hip_runtime.h>

#define B_    4
#define C_    256
#define H_    64
#define W_    64
#define HW_   4096
#define NG_   32
#define CPG_  8
#define KK_   9
#define NOFF_ 18

typedef __attribute__((ext_vector_type(8))) short short8;
typedef __attribute__((ext_vector_type(4))) short short4v;
typedef __attribute__((ext_vector_type(4))) float floatx4;
typedef __attribute__((ext_vector_type(16))) float floatx16;

static __device__ __forceinline__ short f2bf(float f) {
    union { float f; unsigned u; } v; v.f = f;
    unsigned r = v.u + 0x7fff + ((v.u >> 16) & 1);   // RNE
    return (short)(r >> 16);
}
static __device__ __forceinline__ float bf2f(short s) {
    union { unsigned u; float f; } v;
    v.u = ((unsigned)(unsigned short)s) << 16;
    return v.f;
}
// packed f32x2 -> bf16x2 (RNE), single VALU op
static __device__ __forceinline__ unsigned pkbf(float lo, float hi) {
    unsigned r;
    asm("v_cvt_pk_bf16_f32 %0, %1, %2" : "=v"(r) : "v"(lo), "v"(hi));
    return r;
}

// ---------------------------------------------------------------------------
// K1: GroupNorm (32 groups) + ReLU -> bf16 [C][HW]. fp32-input variant.
// ---------------------------------------------------------------------------
__global__ __launch_bounds__(1024) void gn_relu_f32_kernel(
    const float* __restrict__ in, const float* __restrict__ gamma,
    const float* __restrict__ beta, short* __restrict__ outb)
{
    int b = blockIdx.x >> 5;
    int g = blockIdx.x & 31;
    const int N = CPG_ * HW_;              // 32768
    size_t base = ((size_t)(b * C_ + g * CPG_)) * HW_;
    const float4* in4 = (const float4*)(in + base);
    int t = threadIdx.x;

    float s = 0.f, ss = 0.f;
    for (int i = t; i < N / 4; i += 1024) {
        float4 v = in4[i];
        s  += v.x + v.y + v.z + v.w;
        ss += v.x * v.x + v.y * v.y + v.z * v.z + v.w * v.w;
    }
    #pragma unroll
    for (int off = 32; off > 0; off >>= 1) {
        s  += __shfl_down(s, off, 64);
        ss += __shfl_down(ss, off, 64);
    }
    __shared__ float red[32];
    __shared__ float sh_rs, sh_m;
    int wid = t >> 6;
    if ((t & 63) == 0) { red[wid] = s; red[16 + wid] = ss; }
    __syncthreads();
    if (t == 0) {
        float S = 0.f, SS = 0.f;
        #pragma unroll
        for (int i = 0; i < 16; ++i) { S += red[i]; SS += red[16 + i]; }
        float m = S / (float)N;
        float var = SS / (float)N - m * m;
        sh_rs = rsqrtf(var + 1e-5f);
        sh_m = m;
    }
    __syncthreads();
    float rs = sh_rs, m = sh_m;
    short4v* out4 = (short4v*)(outb + base);
    for (int i = t; i < N / 4; i += 1024) {
        int ch = g * CPG_ + (i >> 10);
        float ga = gamma[ch] * rs;
        float be = beta[ch] - m * ga;
        float4 v = in4[i];
        short4v o;
        o.x = f2bf(fmaxf(fmaf(v.x, ga, be), 0.f));
        o.y = f2bf(fmaxf(fmaf(v.y, ga, be), 0.f));
        o.z = f2bf(fmaxf(fmaf(v.z, ga, be), 0.f));
        o.w = f2bf(fmaxf(fmaf(v.w, ga, be), 0.f));
        out4[i] = o;
    }
}

// bf16-input variant (reads layer-1 output y1 in bf16)
__global__ __launch_bounds__(1024) void gn_relu_bf16_kernel(
    const short* __restrict__ in, const float* __restrict__ gamma,
    const float* __restrict__ beta, short* __restrict__ outb)
{
    int b = blockIdx.x >> 5;
    int g = blockIdx.x & 31;
    const int N = CPG_ * HW_;
    size_t base = ((size_t)(b * C_ + g * CPG_)) * HW_;
    const short4v* in4 = (const short4v*)(in + base);
    int t = threadIdx.x;

    float s = 0.f, ss = 0.f;
    for (int i = t; i < N / 4; i += 1024) {
        short4v sv = in4[i];
        float vx = bf2f(sv.x), vy = bf2f(sv.y), vz = bf2f(sv.z), vw = bf2f(sv.w);
        s  += vx + vy + vz + vw;
        ss += vx * vx + vy * vy + vz * vz + vw * vw;
    }
    #pragma unroll
    for (int off = 32; off > 0; off >>= 1) {
        s  += __shfl_down(s, off, 64);
        ss += __shfl_down(ss, off, 64);
    }
    __shared__ float red[32];
    __shared__ float sh_rs, sh_m;
    int wid = t >> 6;
    if ((t & 63) == 0) { red[wid] = s; red[16 + wid] = ss; }
    __syncthreads();
    if (t == 0) {
        float S = 0.f, SS = 0.f;
        #pragma unroll
        for (int i = 0; i < 16; ++i) { S += red[i]; SS += red[16 + i]; }
        float m = S / (float)N;
        float var = SS / (float)N - m * m;
        sh_rs = rsqrtf(var + 1e-5f);
        sh_m = m;
    }
    __syncthreads();
    float rs = sh_rs, m = sh_m;
    short4v* out4 = (short4v*)(outb + base);
    for (int i = t; i < N / 4; i += 1024) {
        int ch = g * CPG_ + (i >> 10);
        float ga = gamma[ch] * rs;
        float be = beta[ch] - m * ga;
        short4v sv = in4[i];
        short4v o;
        o.x = f2bf(fmaxf(fmaf(bf2f(sv.x), ga, be), 0.f));
        o.y = f2bf(fmaxf(fmaf(bf2f(sv.y), ga, be), 0.f));
        o.z = f2bf(fmaxf(fmaf(bf2f(sv.z), ga, be), 0.f));
        o.w = f2bf(fmaxf(fmaf(bf2f(sv.w), ga, be), 0.f));
        out4[i] = o;
    }
}

// ---------------------------------------------------------------------------
// K2: fused {depthwise 7x7 -> fdwt octet-major} AND {transpose hbf -> ht
// [B][HW][C]}. Blocks 0..255: dw7t. Blocks 256..511: trA (XCD-swizzled).
// ---------------------------------------------------------------------------
__global__ __launch_bounds__(256) void dw7t_tr_kernel(
    const short* __restrict__ in,   // hbf [B][C][HW]
    const float* __restrict__ dwk,  // [C][49]
    short* __restrict__ fdwt,       // [B][64][32][64][8]
    short* __restrict__ ht)         // [B][HW][C]
{
    __shared__ __align__(16) char smem[78112];
    int t = threadIdx.x;
    int blk = blockIdx.x;
    if (blk < 256) {
        short (*tile)[38][72] = (short(*)[38][72])smem;          // 43776 B
        float (*wk8)[49]      = (float(*)[49])(smem + 43776);    // 1568 B
        short (*outs)[2048]   = (short(*)[2048])(smem + 45344);  // 32768 B
        int b = blk >> 6, o8 = (blk >> 1) & 31, rh = blk & 1;
        int c0 = o8 * 8;
        unsigned* tz = (unsigned*)smem;
        for (int i = t; i < 10944; i += 256) tz[i] = 0u;         // zero tile
        for (int i = t; i < 392; i += 256)
            wk8[i / 49][i % 49] = dwk[(c0 + i / 49) * 49 + (i % 49)];
        __syncthreads();
        // load 8 planes, rows rh*32-3 .. rh*32+34 (halo), cols at +4 pad
        for (int ch = 0; ch < 8; ++ch) {
            const short* src = in + ((size_t)(b * C_ + c0 + ch)) * HW_;
            for (int i = t; i < 608; i += 256) {
                int rr = i >> 4, xq = i & 15;
                int ry = rh * 32 + rr - 3;
                if (ry >= 0 && ry < 64) {
                    short4v v = *(const short4v*)(src + ry * 64 + xq * 4);
                    *(short4v*)&tile[ch][rr][4 + xq * 4] = v;
                }
            }
        }
        __syncthreads();
        // compute: 4096 quads (ch,y,x0)
        for (int it = 0; it < 16; ++it) {
            int q = it * 256 + t;
            int ch = q >> 9, y = (q >> 4) & 31, x0 = (q & 15) << 2;
            float a0 = 0.f, a1 = 0.f, a2 = 0.f, a3 = 0.f;
            const float* wr0 = wk8[ch];
            #pragma unroll
            for (int dy = 0; dy < 7; ++dy) {
                const short* trw = &tile[ch][y + dy][x0];
                short4v s0 = *(const short4v*)trw;
                short4v s1 = *(const short4v*)(trw + 4);
                short4v s2 = *(const short4v*)(trw + 8);
                float r[12] = {bf2f(s0.x), bf2f(s0.y), bf2f(s0.z), bf2f(s0.w),
                               bf2f(s1.x), bf2f(s1.y), bf2f(s1.z), bf2f(s1.w),
                               bf2f(s2.x), bf2f(s2.y), bf2f(s2.z), bf2f(s2.w)};
                const float* wr = wr0 + dy * 7;
                #pragma unroll
                for (int dx = 0; dx < 7; ++dx) {
                    float wv = wr[dx];
                    a0 = fmaf(r[dx + 1], wv, a0);
                    a1 = fmaf(r[dx + 2], wv, a1);
                    a2 = fmaf(r[dx + 3], wv, a2);
                    a3 = fmaf(r[dx + 4], wv, a3);
                }
            }
            short4v o;
            o.x = f2bf(a0); o.y = f2bf(a1); o.z = f2bf(a2); o.w = f2bf(a3);
            *(short4v*)&outs[ch][y * 64 + x0] = o;
        }
        __syncthreads();
        // octet-major coalesced write: 2048 px-chunks of 16B
        for (int it = 0; it < 8; ++it) {
            int p = it * 256 + t;
            short8 v;
            #pragma unroll
            for (int ch = 0; ch < 8; ++ch) v[ch] = outs[ch][p];
            *(short8*)(fdwt + (((size_t)(b * 64 + rh * 32 + (p >> 6)) * 32 + o8) * 64
                               + (p & 63)) * 8) = v;
        }
    } else {
        unsigned* ltile = (unsigned*)smem;     // 64*132 words = 33792 B
        int q0 = blk - 256;
        int q = ((q0 & 7) << 5) | (q0 >> 3);   // XCD swizzle (matches deform)
        int b = q >> 6;
        int px0 = (q & 63) * 64;
        const short* sb = in + (size_t)b * C_ * HW_;
        int pq4 = t & 15, cphi = t >> 4;
        #pragma unroll
        for (int i = 0; i < 8; ++i) {
            int cp = i * 16 + cphi;            // channel pair 0..127
            const short* r0 = sb + (size_t)(2 * cp) * HW_ + px0 + pq4 * 4;
            short4v lo = *(const short4v*)r0;
            short4v hi = *(const short4v*)(r0 + HW_);
            #pragma unroll
            for (int j = 0; j < 4; ++j) {
                int pl = pq4 * 4 + j;
                unsigned wrd = (unsigned)(unsigned short)lo[j]
                             | ((unsigned)(unsigned short)hi[j] << 16);
                ltile[pl * 132 + (cp ^ ((pl & 7) << 2))] = wrd;
            }
        }
        __syncthreads();
        int co = t & 31, ph2 = t >> 5;
        #pragma unroll
        for (int r = 0; r < 8; ++r) {
            int pl = r * 8 + ph2;
            uint4 v = *(const uint4*)&ltile[pl * 132 + ((co * 4) ^ ((pl & 7) << 2))];
            *(uint4*)(ht + ((size_t)b * HW_ + px0 + pl) * C_ + co * 8) = v;
        }
    }
}

// ---------------------------------------------------------------------------
// K3: pack weights. Round-8 flip: COALESCED fp32 reads, scattered 2B writes
// (was: scattered 4B reads that stall waves on L2 latency; scattered writes
// are fire-and-forget). Dest mapping is the exact inverse of the old forward
// map. Blocks 0..4607: w1/w2. Blocks 4608..4671: pw1/pw2 (unchanged).
// ---------------------------------------------------------------------------
__global__ __launch_bounds__(256) void wpack_all_kernel(
    const float* __restrict__ w1, const float* __restrict__ w2,
    const float* __restrict__ pw1, const float* __restrict__ pw2,
    short* __restrict__ wp1, short* __restrict__ wp2,
    short* __restrict__ ppk1, short* __restrict__ ppk2)
{
    int blk = blockIdx.x;
    if (blk < 4608) {
        const float* w = (blk < 2304) ? w1 : w2;
        short* wp = (blk < 2304) ? wp1 : wp2;
        int src = (blk % 2304) * 256 + threadIdx.x;  // 0..589823, coalesced
        float v = w[src];
        int o = src / (C_ * KK_);                    // src = (o*C + c)*9 + g
        int r = src - o * (C_ * KK_);
        int c = r / KK_;
        int g = r - c * KK_;
        // inverse of: j=idx&7, lane=(idx>>3)&63, ot=(idx>>9)&7, slab=idx>>12;
        //   o=ot*32+(lane&31), c=(slab&15)*16+(lane>>5)*8+j, g=slab>>4
        int ot   = o >> 5;
        int lane = (o & 31) | (((c >> 3) & 1) << 5);
        int j    = c & 7;
        int slab = g * 16 + (c >> 4);
        wp[(slab << 12) | (ot << 9) | (lane << 3) | j] = f2bf(v);
    } else {
        int q = blk - 4608;                          // 0..63
        const float* pw = (q < 32) ? pw1 : pw2;
        short* ppk = (q < 32) ? ppk1 : ppk2;
        int idx = (q & 31) * 256 + threadIdx.x;      // 0..8191
        int j = idx & 7, lane = (idx >> 3) & 63;
        int ot = (idx >> 9) & 1, sl = idx >> 10;     // 0..7
        int o = ot * 16 + (lane & 15);
        int k = sl * 32 + (lane >> 4) * 8 + j;
        ppk[idx] = (o < NOFF_) ? f2bf(pw[o * C_ + k]) : (short)0;
    }
}

// ---------------------------------------------------------------------------
// K4: fused deformable layer -- ROUND-3 structure verbatim (proven 44.5us,
// no spill: acc[2]=32 AGPR, VGPR<=128 at 4 waves/SIMD). Stage A reads the
// octet-major fdwt (proven in r6/r7). One tweak vs r3: all 8 A-fragment
// loads hoisted to the top of each tap's MFMA phase (af[8]) so batch-2's
// L2 latency overlaps batch-1's MFMAs instead of serializing after them.
// ---------------------------------------------------------------------------
__global__ __launch_bounds__(1024, 4) void deform_fused_kernel(
    const short* __restrict__ ht,   const short* __restrict__ fdw,
    const short* __restrict__ ppk,  const float* __restrict__ pwb,
    const short* __restrict__ wp,   const float* __restrict__ bias,
    const float* __restrict__ resid, float* __restrict__ outf,
    short* __restrict__ outb)
{
    int lb = ((blockIdx.x & 7) << 5) | (blockIdx.x >> 3);   // XCD swizzle
    int b = lb >> 6;
    int row = lb & 63;
    __shared__ int   i00[576], i01[576], i10[576], i11[576];
    __shared__ float c00[576], c01[576], c10[576], c11[576];
    __shared__ __align__(16) short sbuf[2][2][8192];  // [buf][panel][64px*128ch] = 64KB
    float* off_lds = (float*)&sbuf[0][0][0];          // 18*64 floats, dead before staging
    int t = threadIdx.x;
    int wv = t >> 6, lane = t & 63;
    int pq = lane >> 4, pr = lane & 15;
    int l31 = lane & 31, hi = lane >> 5;

    // ---- stage A: pw offsets via 16x16x32 MFMA (waves 0..7, full C) ----
    if (wv < 8) {
        int ot = wv & 1, ptw = wv >> 1;
        int px = ptw * 16 + pr;
        const short8* fdw8 = (const short8*)fdw;
        size_t fbase = ((size_t)(b * 64 + row)) * 32;
        const short8* ap = (const short8*)ppk;
        floatx4 pacc = (floatx4){0.f, 0.f, 0.f, 0.f};
        #pragma unroll
        for (int sl = 0; sl < 8; ++sl) {
            short8 af = ap[(sl * 2 + ot) * 64 + lane];
            short8 bf = fdw8[(fbase + sl * 4 + pq) * 64 + px];
            pacc = __builtin_amdgcn_mfma_f32_16x16x32_bf16(af, bf, pacc, 0, 0, 0);
        }
        #pragma unroll
        for (int r = 0; r < 4; ++r) {
            int o = ot * 16 + pq * 4 + r;
            if (o < NOFF_) off_lds[o * 64 + px] = pacc[r] + pwb[o];
        }
    }
    __syncthreads();

    // ---- stage B: bilinear coefficient tables ----
    if (t < 576) {
        int e = t;
        int k = e >> 6, p = e & 63;
        float offy = off_lds[(2 * k) * 64 + p];
        float offx = off_lds[(2 * k + 1) * 64 + p];
        float py = (float)row + (float)(k / 3 - 1) + offy;
        float px = (float)p   + (float)(k % 3 - 1) + offx;
        float y0f = floorf(py), x0f = floorf(px);
        float wy1 = py - y0f, wx1 = px - x0f;
        float wy0 = 1.f - wy1, wx0 = 1.f - wx1;
        float y1f = y0f + 1.f, x1f = x0f + 1.f;
        bool vy0 = (y0f >= 0.f) && (y0f <= 63.f);
        bool vy1 = (y1f >= 0.f) && (y1f <= 63.f);
        bool vx0 = (x0f >= 0.f) && (x0f <= 63.f);
        bool vx1 = (x1f >= 0.f) && (x1f <= 63.f);
        int iy0 = (int)fminf(fmaxf(y0f, 0.f), 63.f);
        int iy1 = (int)fminf(fmaxf(y1f, 0.f), 63.f);
        int ix0 = (int)fminf(fmaxf(x0f, 0.f), 63.f);
        int ix1 = (int)fminf(fmaxf(x1f, 0.f), 63.f);
        i00[e] = iy0 * 64 + ix0; i01[e] = iy0 * 64 + ix1;
        i10[e] = iy1 * 64 + ix0; i11[e] = iy1 * 64 + ix1;
        c00[e] = (vy0 && vx0) ? wy0 * wx0 : 0.f;
        c01[e] = (vy0 && vx1) ? wy0 * wx1 : 0.f;
        c10[e] = (vy1 && vx0) ? wy1 * wx0 : 0.f;
        c11[e] = (vy1 && vx1) ? wy1 * wx1 : 0.f;
    }
    __syncthreads();

    // ---- stage C: 9 taps, full C, double-buffered ----
    int c8a = t & 7;
    int pan = (t >> 3) & 1;
    int spx = t >> 4;                       // 0..63
    const short* hb0 = ht + ((size_t)b * HW_) * C_ + pan * 128 + c8a * 8;
    const short* hb1 = hb0 + 64;            // octet +8
    int slotA = (c8a ^ (spx & 15)) * 8;
    int slotB = ((c8a + 8) ^ (spx & 15)) * 8;
    int srow = spx * 128;

    short8 ra[4], rb[4];
    auto prefetch = [&](int g) {
        int e = g * 64 + spx;
        int a00 = i00[e], a01 = i01[e], a10 = i10[e], a11 = i11[e];
        ra[0] = *(const short8*)(hb0 + (size_t)a00 * C_);
        ra[1] = *(const short8*)(hb0 + (size_t)a01 * C_);
        ra[2] = *(const short8*)(hb0 + (size_t)a10 * C_);
        ra[3] = *(const short8*)(hb0 + (size_t)a11 * C_);
        rb[0] = *(const short8*)(hb1 + (size_t)a00 * C_);
        rb[1] = *(const short8*)(hb1 + (size_t)a01 * C_);
        rb[2] = *(const short8*)(hb1 + (size_t)a10 * C_);
        rb[3] = *(const short8*)(hb1 + (size_t)a11 * C_);
    };
    auto stage_write = [&](int g, int bi) {
        int e = g * 64 + spx;
        float w00 = c00[e], w01 = c01[e], w10 = c10[e], w11 = c11[e];
        uint4 va, vb;
        float f0, f1;
        #define BLEND(R, J) (w00 * bf2f(R[0][J]) + w01 * bf2f(R[1][J]) \
                           + w10 * bf2f(R[2][J]) + w11 * bf2f(R[3][J]))
        f0 = BLEND(ra, 0); f1 = BLEND(ra, 1); va.x = pkbf(f0, f1);
        f0 = BLEND(ra, 2); f1 = BLEND(ra, 3); va.y = pkbf(f0, f1);
        f0 = BLEND(ra, 4); f1 = BLEND(ra, 5); va.z = pkbf(f0, f1);
        f0 = BLEND(ra, 6); f1 = BLEND(ra, 7); va.w = pkbf(f0, f1);
        f0 = BLEND(rb, 0); f1 = BLEND(rb, 1); vb.x = pkbf(f0, f1);
        f0 = BLEND(rb, 2); f1 = BLEND(rb, 3); vb.y = pkbf(f0, f1);
        f0 = BLEND(rb, 4); f1 = BLEND(rb, 5); vb.z = pkbf(f0, f1);
        f0 = BLEND(rb, 6); f1 = BLEND(rb, 7); vb.w = pkbf(f0, f1);
        #undef BLEND
        short* sp = &sbuf[bi][pan][srow];
        *(uint4*)&sp[slotA] = va;
        *(uint4*)&sp[slotB] = vb;
    };

    // wave role: pairId = o-tile (32 rows), half = K-half (128 channels)
    int pairId = wv & 7;
    int half = wv >> 3;

    floatx16 acc[2];
    #pragma unroll
    for (int i = 0; i < 16; ++i) { acc[0][i] = 0.f; acc[1][i] = 0.f; }

    prefetch(0);
    stage_write(0, 0);
    prefetch(1);
    __syncthreads();

    const short8* wp8 = (const short8*)wp;
    int msk = l31 & 15;

    for (int g = 0; g < 9; ++g) {
        const short* sb = &sbuf[g & 1][half][0];
        // hoist ALL 8 A-fragment loads: batch-2's latency hides under batch-1
        short8 af[8];
        #pragma unroll
        for (int q = 0; q < 8; ++q)
            af[q] = wp8[(size_t)(((g * 16 + half * 8 + q) * 8 + pairId) * 64 + lane)];
        #pragma unroll
        for (int q = 0; q < 8; ++q) {
            int so = ((((q << 1) | hi) ^ msk) << 3);
            short8 b0 = *(const short8*)&sb[l31 * 128 + so];
            short8 b1 = *(const short8*)&sb[(32 + l31) * 128 + so];
            acc[0] = __builtin_amdgcn_mfma_f32_32x32x16_bf16(af[q], b0, acc[0], 0, 0, 0);
            acc[1] = __builtin_amdgcn_mfma_f32_32x32x16_bf16(af[q], b1, acc[1], 0, 0, 0);
        }
        if (g + 1 < 9) {
            stage_write(g + 1, (g + 1) & 1);
            if (g + 2 < 9) prefetch(g + 2);
        }
        __syncthreads();
    }

    // ---- combine K-halves in LDS (lane-major planes, conflict-free) ----
    float* xch = (float*)&sbuf[0][0][0];     // 16 regions x 4KB = 64KB
    int wreg = (pairId * 2 + half) * 1024;   // floats
    floatx16 aw = half ? acc[0] : acc[1];
    floatx4* xq = (floatx4*)xch;
    #pragma unroll
    for (int j = 0; j < 4; ++j) {
        floatx4 v = {aw[j * 4 + 0], aw[j * 4 + 1], aw[j * 4 + 2], aw[j * 4 + 3]};
        xq[(wreg >> 2) + j * 64 + lane] = v;
    }
    __syncthreads();
    int rreg = (pairId * 2 + (half ^ 1)) * 1024;
    floatx16 ac = half ? acc[1] : acc[0];
    #pragma unroll
    for (int j = 0; j < 4; ++j) {
        floatx4 v = xq[(rreg >> 2) + j * 64 + lane];
        ac[j * 4 + 0] += v.x; ac[j * 4 + 1] += v.y;
        ac[j * 4 + 2] += v.z; ac[j * 4 + 3] += v.w;
    }

    // ---- epilogue: wave stores its px-tile (pxt = half) ----
    // C/D 32x32: col = lane&31 (px), row = (r&3) + 8*(r>>2) + 4*hi (o)
    #pragma unroll
    for (int r = 0; r < 16; ++r) {
        int o = pairId * 32 + (r & 3) + 8 * (r >> 2) + 4 * hi;
        float v = ac[r] + bias[o];
        size_t ob = ((size_t)(b * C_ + o)) * HW_ + row * 64 + half * 32 + l31;
        if (outf) {
            if (resid) v += resid[ob];
            outf[ob] = v;
        } else {
            outb[ob] = f2bf(v);
        }
    }
}

// ---------------------------------------------------------------------------
extern "C" void kernel_launch(void* const* d_in, const int* in_sizes, int n_in,
                              void* d_out, int out_size, void* d_ws, size_t ws_size,
                              hipStream_t stream)
{
    const float* x     = (const float*)d_in[0];
    const float* gn1_g = (const float*)d_in[1];
    const float* gn1_b = (const float*)d_in[2];
    const float* dw1   = (const float*)d_in[3];
    const float* pw1   = (const float*)d_in[4];
    const float* pwb1  = (const float*)d_in[5];
    const float* w1    = (const float*)d_in[6];
    const float* b1    = (const float*)d_in[7];
    const float* gn2_g = (const float*)d_in[8];
    const float* gn2_b = (const float*)d_in[9];
    const float* dw2   = (const float*)d_in[10];
    const float* pw2   = (const float*)d_in[11];
    const float* pwb2  = (const float*)d_in[12];
    const float* w2    = (const float*)d_in[13];
    const float* b2    = (const float*)d_in[14];
    float* out = (float*)d_out;

    float* ws   = (float*)d_ws;
    short* y1b  = (short*)ws;                  // bf16 [B][C][HW]       (8 MB)
    short* hbf  = (short*)(ws + 2097152);      // bf16 [B][C][HW]       (8 MB)
    short* hbt  = (short*)(ws + 4194304);      // bf16 [B][HW][C]       (8 MB)
    short* fdwt = (short*)(ws + 8388608);      // bf16 [B][64][32][64][8] (8 MB)
    short* wp1  = (short*)(ws + 10485760);     // 589,824 bf16
    short* wp2  = (short*)(ws + 10780672);     // 589,824 bf16
    short* ppk1 = (short*)(ws + 11075584);     // 8,192 bf16
    short* ppk2 = (short*)(ws + 11079680);     // 8,192 bf16

    wpack_all_kernel<<<4672, 256, 0, stream>>>(w1, w2, pw1, pw2,
                                               wp1, wp2, ppk1, ppk2);

    // layer 1
    gn_relu_f32_kernel<<<B_ * NG_, 1024, 0, stream>>>(x, gn1_g, gn1_b, hbf);
    dw7t_tr_kernel<<<512, 256, 0, stream>>>(hbf, dw1, fdwt, hbt);
    deform_fused_kernel<<<B_ * H_, 1024, 0, stream>>>(
        hbt, fdwt, ppk1, pwb1, wp1, b1, nullptr, nullptr, y1b);

    // layer 2 (+ residual x)
    gn_relu_bf16_kernel<<<B_ * NG_, 1024, 0, stream>>>(y1b, gn2_g, gn2_b, hbf);
    dw7t_tr_kernel<<<512, 256, 0, stream>>>(hbf, dw2, fdwt, hbt);
    deform_fused_kernel<<<B_ * H_, 1024, 0, stream>>>(
        hbt, fdwt, ppk2, pwb2, wp2, b2, x, out, nullptr);
}

// Round 10
// 254.285 us; speedup vs baseline: 1.0899x; 1.0604x over previous
//
#include <hip/hip_runtime.h>

#define B_    4
#define C_    256
#define H_    64
#define W_    64
#define HW_   4096
#define NG_   32
#define CPG_  8
#define KK_   9
#define NOFF_ 18

typedef __attribute__((ext_vector_type(8))) short short8;
typedef __attribute__((ext_vector_type(4))) short short4v;
typedef __attribute__((ext_vector_type(4))) float floatx4;
typedef __attribute__((ext_vector_type(16))) float floatx16;

static __device__ __forceinline__ short f2bf(float f) {
    union { float f; unsigned u; } v; v.f = f;
    unsigned r = v.u + 0x7fff + ((v.u >> 16) & 1);   // RNE
    return (short)(r >> 16);
}
static __device__ __forceinline__ float bf2f(short s) {
    union { unsigned u; float f; } v;
    v.u = ((unsigned)(unsigned short)s) << 16;
    return v.f;
}
// packed f32x2 -> bf16x2 (RNE), single VALU op
static __device__ __forceinline__ unsigned pkbf(float lo, float hi) {
    unsigned r;
    asm("v_cvt_pk_bf16_f32 %0, %1, %2" : "=v"(r) : "v"(lo), "v"(hi));
    return r;
}

// ---------------------------------------------------------------------------
// K1: GroupNorm (32 groups) + ReLU -> bf16 [C][HW]. fp32-input variant.
// ---------------------------------------------------------------------------
__global__ __launch_bounds__(1024) void gn_relu_f32_kernel(
    const float* __restrict__ in, const float* __restrict__ gamma,
    const float* __restrict__ beta, short* __restrict__ outb)
{
    int b = blockIdx.x >> 5;
    int g = blockIdx.x & 31;
    const int N = CPG_ * HW_;              // 32768
    size_t base = ((size_t)(b * C_ + g * CPG_)) * HW_;
    const float4* in4 = (const float4*)(in + base);
    int t = threadIdx.x;

    float s = 0.f, ss = 0.f;
    for (int i = t; i < N / 4; i += 1024) {
        float4 v = in4[i];
        s  += v.x + v.y + v.z + v.w;
        ss += v.x * v.x + v.y * v.y + v.z * v.z + v.w * v.w;
    }
    #pragma unroll
    for (int off = 32; off > 0; off >>= 1) {
        s  += __shfl_down(s, off, 64);
        ss += __shfl_down(ss, off, 64);
    }
    __shared__ float red[32];
    __shared__ float sh_rs, sh_m;
    int wid = t >> 6;
    if ((t & 63) == 0) { red[wid] = s; red[16 + wid] = ss; }
    __syncthreads();
    if (t == 0) {
        float S = 0.f, SS = 0.f;
        #pragma unroll
        for (int i = 0; i < 16; ++i) { S += red[i]; SS += red[16 + i]; }
        float m = S / (float)N;
        float var = SS / (float)N - m * m;
        sh_rs = rsqrtf(var + 1e-5f);
        sh_m = m;
    }
    __syncthreads();
    float rs = sh_rs, m = sh_m;
    short4v* out4 = (short4v*)(outb + base);
    for (int i = t; i < N / 4; i += 1024) {
        int ch = g * CPG_ + (i >> 10);
        float ga = gamma[ch] * rs;
        float be = beta[ch] - m * ga;
        float4 v = in4[i];
        short4v o;
        o.x = f2bf(fmaxf(fmaf(v.x, ga, be), 0.f));
        o.y = f2bf(fmaxf(fmaf(v.y, ga, be), 0.f));
        o.z = f2bf(fmaxf(fmaf(v.z, ga, be), 0.f));
        o.w = f2bf(fmaxf(fmaf(v.w, ga, be), 0.f));
        out4[i] = o;
    }
}

// bf16-input variant (reads layer-1 output y1 in bf16)
__global__ __launch_bounds__(1024) void gn_relu_bf16_kernel(
    const short* __restrict__ in, const float* __restrict__ gamma,
    const float* __restrict__ beta, short* __restrict__ outb)
{
    int b = blockIdx.x >> 5;
    int g = blockIdx.x & 31;
    const int N = CPG_ * HW_;
    size_t base = ((size_t)(b * C_ + g * CPG_)) * HW_;
    const short4v* in4 = (const short4v*)(in + base);
    int t = threadIdx.x;

    float s = 0.f, ss = 0.f;
    for (int i = t; i < N / 4; i += 1024) {
        short4v sv = in4[i];
        float vx = bf2f(sv.x), vy = bf2f(sv.y), vz = bf2f(sv.z), vw = bf2f(sv.w);
        s  += vx + vy + vz + vw;
        ss += vx * vx + vy * vy + vz * vz + vw * vw;
    }
    #pragma unroll
    for (int off = 32; off > 0; off >>= 1) {
        s  += __shfl_down(s, off, 64);
        ss += __shfl_down(ss, off, 64);
    }
    __shared__ float red[32];
    __shared__ float sh_rs, sh_m;
    int wid = t >> 6;
    if ((t & 63) == 0) { red[wid] = s; red[16 + wid] = ss; }
    __syncthreads();
    if (t == 0) {
        float S = 0.f, SS = 0.f;
        #pragma unroll
        for (int i = 0; i < 16; ++i) { S += red[i]; SS += red[16 + i]; }
        float m = S / (float)N;
        float var = SS / (float)N - m * m;
        sh_rs = rsqrtf(var + 1e-5f);
        sh_m = m;
    }
    __syncthreads();
    float rs = sh_rs, m = sh_m;
    short4v* out4 = (short4v*)(outb + base);
    for (int i = t; i < N / 4; i += 1024) {
        int ch = g * CPG_ + (i >> 10);
        float ga = gamma[ch] * rs;
        float be = beta[ch] - m * ga;
        short4v sv = in4[i];
        short4v o;
        o.x = f2bf(fmaxf(fmaf(bf2f(sv.x), ga, be), 0.f));
        o.y = f2bf(fmaxf(fmaf(bf2f(sv.y), ga, be), 0.f));
        o.z = f2bf(fmaxf(fmaf(bf2f(sv.z), ga, be), 0.f));
        o.w = f2bf(fmaxf(fmaf(bf2f(sv.w), ga, be), 0.f));
        out4[i] = o;
    }
}

// ---------------------------------------------------------------------------
// K2: fused {depthwise 7x7 -> fdwt octet-major} AND {transpose hbf -> ht
// [B][HW][C]}. Blocks 0..255: dw7t. Blocks 256..511: trA (XCD-swizzled).
// ---------------------------------------------------------------------------
__global__ __launch_bounds__(256) void dw7t_tr_kernel(
    const short* __restrict__ in,   // hbf [B][C][HW]
    const float* __restrict__ dwk,  // [C][49]
    short* __restrict__ fdwt,       // [B][64][32][64][8]
    short* __restrict__ ht)         // [B][HW][C]
{
    __shared__ __align__(16) char smem[78112];
    int t = threadIdx.x;
    int blk = blockIdx.x;
    if (blk < 256) {
        short (*tile)[38][72] = (short(*)[38][72])smem;          // 43776 B
        float (*wk8)[49]      = (float(*)[49])(smem + 43776);    // 1568 B
        short (*outs)[2048]   = (short(*)[2048])(smem + 45344);  // 32768 B
        int b = blk >> 6, o8 = (blk >> 1) & 31, rh = blk & 1;
        int c0 = o8 * 8;
        unsigned* tz = (unsigned*)smem;
        for (int i = t; i < 10944; i += 256) tz[i] = 0u;         // zero tile
        for (int i = t; i < 392; i += 256)
            wk8[i / 49][i % 49] = dwk[(c0 + i / 49) * 49 + (i % 49)];
        __syncthreads();
        // load 8 planes, rows rh*32-3 .. rh*32+34 (halo), cols at +4 pad
        for (int ch = 0; ch < 8; ++ch) {
            const short* src = in + ((size_t)(b * C_ + c0 + ch)) * HW_;
            for (int i = t; i < 608; i += 256) {
                int rr = i >> 4, xq = i & 15;
                int ry = rh * 32 + rr - 3;
                if (ry >= 0 && ry < 64) {
                    short4v v = *(const short4v*)(src + ry * 64 + xq * 4);
                    *(short4v*)&tile[ch][rr][4 + xq * 4] = v;
                }
            }
        }
        __syncthreads();
        // compute: 4096 quads (ch,y,x0)
        for (int it = 0; it < 16; ++it) {
            int q = it * 256 + t;
            int ch = q >> 9, y = (q >> 4) & 31, x0 = (q & 15) << 2;
            float a0 = 0.f, a1 = 0.f, a2 = 0.f, a3 = 0.f;
            const float* wr0 = wk8[ch];
            #pragma unroll
            for (int dy = 0; dy < 7; ++dy) {
                const short* trw = &tile[ch][y + dy][x0];
                short4v s0 = *(const short4v*)trw;
                short4v s1 = *(const short4v*)(trw + 4);
                short4v s2 = *(const short4v*)(trw + 8);
                float r[12] = {bf2f(s0.x), bf2f(s0.y), bf2f(s0.z), bf2f(s0.w),
                               bf2f(s1.x), bf2f(s1.y), bf2f(s1.z), bf2f(s1.w),
                               bf2f(s2.x), bf2f(s2.y), bf2f(s2.z), bf2f(s2.w)};
                const float* wr = wr0 + dy * 7;
                #pragma unroll
                for (int dx = 0; dx < 7; ++dx) {
                    float wv = wr[dx];
                    a0 = fmaf(r[dx + 1], wv, a0);
                    a1 = fmaf(r[dx + 2], wv, a1);
                    a2 = fmaf(r[dx + 3], wv, a2);
                    a3 = fmaf(r[dx + 4], wv, a3);
                }
            }
            short4v o;
            o.x = f2bf(a0); o.y = f2bf(a1); o.z = f2bf(a2); o.w = f2bf(a3);
            *(short4v*)&outs[ch][y * 64 + x0] = o;
        }
        __syncthreads();
        // octet-major coalesced write: 2048 px-chunks of 16B
        for (int it = 0; it < 8; ++it) {
            int p = it * 256 + t;
            short8 v;
            #pragma unroll
            for (int ch = 0; ch < 8; ++ch) v[ch] = outs[ch][p];
            *(short8*)(fdwt + (((size_t)(b * 64 + rh * 32 + (p >> 6)) * 32 + o8) * 64
                               + (p & 63)) * 8) = v;
        }
    } else {
        unsigned* ltile = (unsigned*)smem;     // 64*132 words = 33792 B
        int q0 = blk - 256;
        int q = ((q0 & 7) << 5) | (q0 >> 3);   // XCD swizzle (matches deform)
        int b = q >> 6;
        int px0 = (q & 63) * 64;
        const short* sb = in + (size_t)b * C_ * HW_;
        int pq4 = t & 15, cphi = t >> 4;
        #pragma unroll
        for (int i = 0; i < 8; ++i) {
            int cp = i * 16 + cphi;            // channel pair 0..127
            const short* r0 = sb + (size_t)(2 * cp) * HW_ + px0 + pq4 * 4;
            short4v lo = *(const short4v*)r0;
            short4v hi = *(const short4v*)(r0 + HW_);
            #pragma unroll
            for (int j = 0; j < 4; ++j) {
                int pl = pq4 * 4 + j;
                unsigned wrd = (unsigned)(unsigned short)lo[j]
                             | ((unsigned)(unsigned short)hi[j] << 16);
                ltile[pl * 132 + (cp ^ ((pl & 7) << 2))] = wrd;
            }
        }
        __syncthreads();
        int co = t & 31, ph2 = t >> 5;
        #pragma unroll
        for (int r = 0; r < 8; ++r) {
            int pl = r * 8 + ph2;
            uint4 v = *(const uint4*)&ltile[pl * 132 + ((co * 4) ^ ((pl & 7) << 2))];
            *(uint4*)(ht + ((size_t)b * HW_ + px0 + pl) * C_ + co * 8) = v;
        }
    }
}

// ---------------------------------------------------------------------------
// K3: pack weights. Coalesced fp32 reads, scattered 2B writes.
// Blocks 0..4607: w1/w2. Blocks 4608..4671: pw1/pw2.
// ---------------------------------------------------------------------------
__global__ __launch_bounds__(256) void wpack_all_kernel(
    const float* __restrict__ w1, const float* __restrict__ w2,
    const float* __restrict__ pw1, const float* __restrict__ pw2,
    short* __restrict__ wp1, short* __restrict__ wp2,
    short* __restrict__ ppk1, short* __restrict__ ppk2)
{
    int blk = blockIdx.x;
    if (blk < 4608) {
        const float* w = (blk < 2304) ? w1 : w2;
        short* wp = (blk < 2304) ? wp1 : wp2;
        int src = (blk % 2304) * 256 + threadIdx.x;  // 0..589823, coalesced
        float v = w[src];
        int o = src / (C_ * KK_);                    // src = (o*C + c)*9 + g
        int r = src - o * (C_ * KK_);
        int c = r / KK_;
        int g = r - c * KK_;
        int ot   = o >> 5;
        int lane = (o & 31) | (((c >> 3) & 1) << 5);
        int j    = c & 7;
        int slab = g * 16 + (c >> 4);
        wp[(slab << 12) | (ot << 9) | (lane << 3) | j] = f2bf(v);
    } else {
        int q = blk - 4608;                          // 0..63
        const float* pw = (q < 32) ? pw1 : pw2;
        short* ppk = (q < 32) ? ppk1 : ppk2;
        int idx = (q & 31) * 256 + threadIdx.x;      // 0..8191
        int j = idx & 7, lane = (idx >> 3) & 63;
        int ot = (idx >> 9) & 1, sl = idx >> 10;     // 0..7
        int o = ot * 16 + (lane & 15);
        int k = sl * 32 + (lane >> 4) * 8 + j;
        ppk[idx] = (o < NOFF_) ? f2bf(pw[o * C_ + k]) : (short)0;
    }
}

// ---------------------------------------------------------------------------
// K4: fused deformable layer -- PRODUCER/CONSUMER wave specialization,
// UNIFIED-BARRIER form (round-9 resubmit; r9 container failure may have been
// a divergent-barrier hang, so every __syncthreads now sits in wave-common
// code -- the role branch is INSIDE each barrier interval).
// One block (1024 thr = 16 waves) per (b,row), XCD-swizzled.
// Waves 0..7 = CONSUMERS: wave wv owns o-tile wv, FULL K (16 slabs), both
//   px-tiles (32 MFMA/tap, acc = 2 x fx16 = 32 AGPR, no K-combine).
// Waves 8..15 = PRODUCERS: gather+blend+LDS-write the NEXT tap's buffer.
// Mechanism: r3's lockstep summed pipe demands (L2 4.6K + LDS 3K + VALU
// 3.5K + MFMA 2.1K = 11.9K cyc/tap = 44.5us). Specialization runs producer
// L2+VALU concurrently with consumer LDS+MFMA -> tap ~ max(pipes).
// ---------------------------------------------------------------------------
__global__ __launch_bounds__(1024, 4) void deform_fused_kernel(
    const short* __restrict__ ht,   const short* __restrict__ fdw,
    const short* __restrict__ ppk,  const float* __restrict__ pwb,
    const short* __restrict__ wp,   const float* __restrict__ bias,
    const float* __restrict__ resid, float* __restrict__ outf,
    short* __restrict__ outb)
{
    int lb = ((blockIdx.x & 7) << 5) | (blockIdx.x >> 3);   // XCD swizzle
    int b = lb >> 6;
    int row = lb & 63;
    __shared__ int   i00[576], i01[576], i10[576], i11[576];
    __shared__ float c00[576], c01[576], c10[576], c11[576];
    __shared__ __align__(16) short sbuf[2][2][8192];  // [buf][panel][64px*128ch] = 64KB
    float* off_lds = (float*)&sbuf[0][0][0];          // 18*64 floats, dead before staging
    int t = threadIdx.x;
    int wv = t >> 6, lane = t & 63;
    int pq = lane >> 4, pr = lane & 15;
    int l31 = lane & 31, hi = lane >> 5;

    // ---- stage A: pw offsets via 16x16x32 MFMA (waves 0..7, full C) ----
    if (wv < 8) {
        int ot = wv & 1, ptw = wv >> 1;
        int px = ptw * 16 + pr;
        const short8* fdw8 = (const short8*)fdw;
        size_t fbase = ((size_t)(b * 64 + row)) * 32;
        const short8* ap = (const short8*)ppk;
        floatx4 pacc = (floatx4){0.f, 0.f, 0.f, 0.f};
        #pragma unroll
        for (int sl = 0; sl < 8; ++sl) {
            short8 af = ap[(sl * 2 + ot) * 64 + lane];
            short8 bf = fdw8[(fbase + sl * 4 + pq) * 64 + px];
            pacc = __builtin_amdgcn_mfma_f32_16x16x32_bf16(af, bf, pacc, 0, 0, 0);
        }
        #pragma unroll
        for (int r = 0; r < 4; ++r) {
            int o = ot * 16 + pq * 4 + r;
            if (o < NOFF_) off_lds[o * 64 + px] = pacc[r] + pwb[o];
        }
    }
    __syncthreads();

    // ---- stage B: bilinear coefficient tables ----
    if (t < 576) {
        int e = t;
        int k = e >> 6, p = e & 63;
        float offy = off_lds[(2 * k) * 64 + p];
        float offx = off_lds[(2 * k + 1) * 64 + p];
        float py = (float)row + (float)(k / 3 - 1) + offy;
        float px = (float)p   + (float)(k % 3 - 1) + offx;
        float y0f = floorf(py), x0f = floorf(px);
        float wy1 = py - y0f, wx1 = px - x0f;
        float wy0 = 1.f - wy1, wx0 = 1.f - wx1;
        float y1f = y0f + 1.f, x1f = x0f + 1.f;
        bool vy0 = (y0f >= 0.f) && (y0f <= 63.f);
        bool vy1 = (y1f >= 0.f) && (y1f <= 63.f);
        bool vx0 = (x0f >= 0.f) && (x0f <= 63.f);
        bool vx1 = (x1f >= 0.f) && (x1f <= 63.f);
        int iy0 = (int)fminf(fmaxf(y0f, 0.f), 63.f);
        int iy1 = (int)fminf(fmaxf(y1f, 0.f), 63.f);
        int ix0 = (int)fminf(fmaxf(x0f, 0.f), 63.f);
        int ix1 = (int)fminf(fmaxf(x1f, 0.f), 63.f);
        i00[e] = iy0 * 64 + ix0; i01[e] = iy0 * 64 + ix1;
        i10[e] = iy1 * 64 + ix0; i11[e] = iy1 * 64 + ix1;
        c00[e] = (vy0 && vx0) ? wy0 * wx0 : 0.f;
        c01[e] = (vy0 && vx1) ? wy0 * wx1 : 0.f;
        c10[e] = (vy1 && vx0) ? wy1 * wx0 : 0.f;
        c11[e] = (vy1 && vx1) ? wy1 * wx1 : 0.f;
    }
    __syncthreads();

    int msk = l31 & 15;

    // ---- role-specific setup (no barriers inside) ----
    const short8* wp8 = (const short8*)wp;
    floatx16 acc0, acc1;
    #pragma unroll
    for (int i = 0; i < 16; ++i) { acc0[i] = 0.f; acc1[i] = 0.f; }

    int tp = t & 511;                   // producer thread id (waves 8..15)
    int pj = tp & 7;                    // octet job 0..7
    int psx = tp >> 3;                  // px 0..63
    const short* base = ht + ((size_t)b * HW_) * C_;
    const short* pb0 = base + pj * 8;           // pan0, c8 = pj
    const short* pb1 = pb0 + 64;                // pan0, c8 = pj+8
    const short* pb2 = base + 128 + pj * 8;     // pan1, c8 = pj
    const short* pb3 = pb2 + 64;                // pan1, c8 = pj+8
    int sl0 = (pj ^ (psx & 15)) * 8;
    int sl1 = ((pj + 8) ^ (psx & 15)) * 8;
    int psrow = psx * 128;

    auto pstage = [&](int g, int bi) {
        int e = g * 64 + psx;
        int a00 = i00[e], a01 = i01[e], a10 = i10[e], a11 = i11[e];
        float w00 = c00[e], w01 = c01[e], w10 = c10[e], w11 = c11[e];
        short8 r0[4], r1[4], r2[4], r3[4];
        r0[0] = *(const short8*)(pb0 + (size_t)a00 * C_);
        r0[1] = *(const short8*)(pb0 + (size_t)a01 * C_);
        r0[2] = *(const short8*)(pb0 + (size_t)a10 * C_);
        r0[3] = *(const short8*)(pb0 + (size_t)a11 * C_);
        r1[0] = *(const short8*)(pb1 + (size_t)a00 * C_);
        r1[1] = *(const short8*)(pb1 + (size_t)a01 * C_);
        r1[2] = *(const short8*)(pb1 + (size_t)a10 * C_);
        r1[3] = *(const short8*)(pb1 + (size_t)a11 * C_);
        r2[0] = *(const short8*)(pb2 + (size_t)a00 * C_);
        r2[1] = *(const short8*)(pb2 + (size_t)a01 * C_);
        r2[2] = *(const short8*)(pb2 + (size_t)a10 * C_);
        r2[3] = *(const short8*)(pb2 + (size_t)a11 * C_);
        r3[0] = *(const short8*)(pb3 + (size_t)a00 * C_);
        r3[1] = *(const short8*)(pb3 + (size_t)a01 * C_);
        r3[2] = *(const short8*)(pb3 + (size_t)a10 * C_);
        r3[3] = *(const short8*)(pb3 + (size_t)a11 * C_);
        #define BLEND(R, J) (w00 * bf2f(R[0][J]) + w01 * bf2f(R[1][J]) \
                           + w10 * bf2f(R[2][J]) + w11 * bf2f(R[3][J]))
        uint4 v;
        v.x = pkbf(BLEND(r0, 0), BLEND(r0, 1));
        v.y = pkbf(BLEND(r0, 2), BLEND(r0, 3));
        v.z = pkbf(BLEND(r0, 4), BLEND(r0, 5));
        v.w = pkbf(BLEND(r0, 6), BLEND(r0, 7));
        *(uint4*)&sbuf[bi][0][psrow + sl0] = v;
        v.x = pkbf(BLEND(r1, 0), BLEND(r1, 1));
        v.y = pkbf(BLEND(r1, 2), BLEND(r1, 3));
        v.z = pkbf(BLEND(r1, 4), BLEND(r1, 5));
        v.w = pkbf(BLEND(r1, 6), BLEND(r1, 7));
        *(uint4*)&sbuf[bi][0][psrow + sl1] = v;
        v.x = pkbf(BLEND(r2, 0), BLEND(r2, 1));
        v.y = pkbf(BLEND(r2, 2), BLEND(r2, 3));
        v.z = pkbf(BLEND(r2, 4), BLEND(r2, 5));
        v.w = pkbf(BLEND(r2, 6), BLEND(r2, 7));
        *(uint4*)&sbuf[bi][1][psrow + sl0] = v;
        v.x = pkbf(BLEND(r3, 0), BLEND(r3, 1));
        v.y = pkbf(BLEND(r3, 2), BLEND(r3, 3));
        v.z = pkbf(BLEND(r3, 4), BLEND(r3, 5));
        v.w = pkbf(BLEND(r3, 6), BLEND(r3, 7));
        *(uint4*)&sbuf[bi][1][psrow + sl1] = v;
        #undef BLEND
    };

    // ---- prologue: producers stage tap 0 (wave-common barrier after) ----
    if (wv >= 8) pstage(0, 0);
    __syncthreads();

    // ---- unified tap loop: barrier is wave-common; role branch inside ----
    for (int g = 0; g < 9; ++g) {
        if (wv < 8) {
            const short* sb0 = &sbuf[g & 1][0][0];
            const short* sb1 = &sbuf[g & 1][1][0];
            #pragma unroll
            for (int bb = 0; bb < 4; ++bb) {
                short8 af[4];
                #pragma unroll
                for (int q = 0; q < 4; ++q)
                    af[q] = wp8[(size_t)(((g * 16 + bb * 4 + q) * 8 + wv) * 64 + lane)];
                #pragma unroll
                for (int q = 0; q < 4; ++q) {
                    int s = bb * 4 + q;                  // slab 0..15
                    const short* sbp = (s < 8) ? sb0 : sb1;
                    int so = ((((s & 7) * 2 + hi) ^ msk) << 3);
                    short8 b0 = *(const short8*)&sbp[l31 * 128 + so];
                    short8 b1 = *(const short8*)&sbp[(32 + l31) * 128 + so];
                    acc0 = __builtin_amdgcn_mfma_f32_32x32x16_bf16(af[q], b0, acc0, 0, 0, 0);
                    acc1 = __builtin_amdgcn_mfma_f32_32x32x16_bf16(af[q], b1, acc1, 0, 0, 0);
                }
            }
        } else {
            if (g + 1 < 9) pstage(g + 1, (g + 1) & 1);
        }
        __syncthreads();
    }

    // ---- epilogue (consumers): full-K acc, o-tile wv, both px-tiles ----
    // C/D 32x32: col = lane&31 (px), row = (r&3) + 8*(r>>2) + 4*hi (o)
    if (wv < 8) {
        #pragma unroll
        for (int r = 0; r < 16; ++r) {
            int o = wv * 32 + (r & 3) + 8 * (r >> 2) + 4 * hi;
            float bo = bias[o];
            float v0 = acc0[r] + bo;
            float v1 = acc1[r] + bo;
            size_t ob = ((size_t)(b * C_ + o)) * HW_ + row * 64 + l31;
            if (outf) {
                if (resid) { v0 += resid[ob]; v1 += resid[ob + 32]; }
                outf[ob] = v0;
                outf[ob + 32] = v1;
            } else {
                outb[ob] = f2bf(v0);
                outb[ob + 32] = f2bf(v1);
            }
        }
    }
}

// ---------------------------------------------------------------------------
extern "C" void kernel_launch(void* const* d_in, const int* in_sizes, int n_in,
                              void* d_out, int out_size, void* d_ws, size_t ws_size,
                              hipStream_t stream)
{
    const float* x     = (const float*)d_in[0];
    const float* gn1_g = (const float*)d_in[1];
    const float* gn1_b = (const float*)d_in[2];
    const float* dw1   = (const float*)d_in[3];
    const float* pw1   = (const float*)d_in[4];
    const float* pwb1  = (const float*)d_in[5];
    const float* w1    = (const float*)d_in[6];
    const float* b1    = (const float*)d_in[7];
    const float* gn2_g = (const float*)d_in[8];
    const float* gn2_b = (const float*)d_in[9];
    const float* dw2   = (const float*)d_in[10];
    const float* pw2   = (const float*)d_in[11];
    const float* pwb2  = (const float*)d_in[12];
    const float* w2    = (const float*)d_in[13];
    const float* b2    = (const float*)d_in[14];
    float* out = (float*)d_out;

    float* ws   = (float*)d_ws;
    short* y1b  = (short*)ws;                  // bf16 [B][C][HW]       (8 MB)
    short* hbf  = (short*)(ws + 2097152);      // bf16 [B][C][HW]       (8 MB)
    short* hbt  = (short*)(ws + 4194304);      // bf16 [B][HW][C]       (8 MB)
    short* fdwt = (short*)(ws + 8388608);      // bf16 [B][64][32][64][8] (8 MB)
    short* wp1  = (short*)(ws + 10485760);     // 589,824 bf16
    short* wp2  = (short*)(ws + 10780672);     // 589,824 bf16
    short* ppk1 = (short*)(ws + 11075584);     // 8,192 bf16
    short* ppk2 = (short*)(ws + 11079680);     // 8,192 bf16

    wpack_all_kernel<<<4672, 256, 0, stream>>>(w1, w2, pw1, pw2,
                                               wp1, wp2, ppk1, ppk2);

    // layer 1
    gn_relu_f32_kernel<<<B_ * NG_, 1024, 0, stream>>>(x, gn1_g, gn1_b, hbf);
    dw7t_tr_kernel<<<512, 256, 0, stream>>>(hbf, dw1, fdwt, hbt);
    deform_fused_kernel<<<B_ * H_, 1024, 0, stream>>>(
        hbt, fdwt, ppk1, pwb1, wp1, b1, nullptr, nullptr, y1b);

    // layer 2 (+ residual x)
    gn_relu_bf16_kernel<<<B_ * NG_, 1024, 0, stream>>>(y1b, gn2_g, gn2_b, hbf);
    dw7t_tr_kernel<<<512, 256, 0, stream>>>(hbf, dw2, fdwt, hbt);
    deform_fused_kernel<<<B_ * H_, 1024, 0, stream>>>(
        hbt, fdwt, ppk2, pwb2, wp2, b2, x, out, nullptr);
}

// Round 11
// 242.770 us; speedup vs baseline: 1.1416x; 1.0474x over previous
//
#include <hip/hip_runtime.h>

#define B_    4
#define C_    256
#define H_    64
#define W_    64
#define HW_   4096
#define NG_   32
#define CPG_  8
#define KK_   9
#define NOFF_ 18

typedef __attribute__((ext_vector_type(8))) short short8;
typedef __attribute__((ext_vector_type(4))) short short4v;
typedef __attribute__((ext_vector_type(4))) float floatx4;
typedef __attribute__((ext_vector_type(16))) float floatx16;

static __device__ __forceinline__ short f2bf(float f) {
    union { float f; unsigned u; } v; v.f = f;
    unsigned r = v.u + 0x7fff + ((v.u >> 16) & 1);   // RNE
    return (short)(r >> 16);
}
static __device__ __forceinline__ float bf2f(short s) {
    union { unsigned u; float f; } v;
    v.u = ((unsigned)(unsigned short)s) << 16;
    return v.f;
}
// packed f32x2 -> bf16x2 (RNE), single VALU op
static __device__ __forceinline__ unsigned pkbf(float lo, float hi) {
    unsigned r;
    asm("v_cvt_pk_bf16_f32 %0, %1, %2" : "=v"(r) : "v"(lo), "v"(hi));
    return r;
}

// ---------------------------------------------------------------------------
// K1: GroupNorm (32 groups) + ReLU -> bf16 [C][HW]. fp32-input, LDS-cached:
// the (b,group) slab (128 KB) is kept in LDS so the normalize pass does NOT
// re-read 16.8 MB from global (was: two full global read passes).
// ---------------------------------------------------------------------------
__global__ __launch_bounds__(1024) void gn_relu_f32_kernel(
    const float* __restrict__ in, const float* __restrict__ gamma,
    const float* __restrict__ beta, short* __restrict__ outb)
{
    __shared__ float cache[32768];         // 128 KB
    __shared__ float red[32];
    __shared__ float sh_rs, sh_m;
    int b = blockIdx.x >> 5;
    int g = blockIdx.x & 31;
    const int N = CPG_ * HW_;              // 32768
    size_t base = ((size_t)(b * C_ + g * CPG_)) * HW_;
    const float4* in4 = (const float4*)(in + base);
    int t = threadIdx.x;

    float s = 0.f, ss = 0.f;
    for (int i = t; i < N / 4; i += 1024) {
        float4 v = in4[i];
        *(float4*)&cache[i * 4] = v;
        s  += v.x + v.y + v.z + v.w;
        ss += v.x * v.x + v.y * v.y + v.z * v.z + v.w * v.w;
    }
    #pragma unroll
    for (int off = 32; off > 0; off >>= 1) {
        s  += __shfl_down(s, off, 64);
        ss += __shfl_down(ss, off, 64);
    }
    int wid = t >> 6;
    if ((t & 63) == 0) { red[wid] = s; red[16 + wid] = ss; }
    __syncthreads();
    if (t == 0) {
        float S = 0.f, SS = 0.f;
        #pragma unroll
        for (int i = 0; i < 16; ++i) { S += red[i]; SS += red[16 + i]; }
        float m = S / (float)N;
        float var = SS / (float)N - m * m;
        sh_rs = rsqrtf(var + 1e-5f);
        sh_m = m;
    }
    __syncthreads();
    float rs = sh_rs, m = sh_m;
    short4v* out4 = (short4v*)(outb + base);
    for (int i = t; i < N / 4; i += 1024) {
        int ch = g * CPG_ + (i >> 10);
        float ga = gamma[ch] * rs;
        float be = beta[ch] - m * ga;
        float4 v = *(const float4*)&cache[i * 4];
        short4v o;
        o.x = f2bf(fmaxf(fmaf(v.x, ga, be), 0.f));
        o.y = f2bf(fmaxf(fmaf(v.y, ga, be), 0.f));
        o.z = f2bf(fmaxf(fmaf(v.z, ga, be), 0.f));
        o.w = f2bf(fmaxf(fmaf(v.w, ga, be), 0.f));
        out4[i] = o;
    }
}

// ---------------------------------------------------------------------------
// K1b: GroupNorm APPLY (stats precomputed by deform-1's epilogue) + ReLU.
// Pure single-pass normalize: grid 512 = (b, g, quarter), full GPU.
// ---------------------------------------------------------------------------
__global__ __launch_bounds__(1024) void gn_apply_bf16_kernel(
    const short* __restrict__ in, const float* __restrict__ gstats,
    const float* __restrict__ gamma, const float* __restrict__ beta,
    short* __restrict__ outb)
{
    int blk = blockIdx.x;                  // (b<<7) | (g<<2) | q
    int b = blk >> 7, g = (blk >> 2) & 31, qq = blk & 3;
    const float Ninv = 1.f / (float)(CPG_ * HW_);
    int sidx = b * 32 + g;
    float m   = gstats[sidx] * Ninv;
    float var = gstats[128 + sidx] * Ninv - m * m;
    float rs  = rsqrtf(var + 1e-5f);
    size_t base = ((size_t)(b * C_ + g * CPG_)) * HW_;
    const short4v* in4 = (const short4v*)(in + base);
    short4v* out4 = (short4v*)(outb + base);
    int t = threadIdx.x;
    int i0 = qq * 2048;
    for (int i = i0 + t; i < i0 + 2048; i += 1024) {
        int ch = g * CPG_ + (i >> 10);
        float ga = gamma[ch] * rs;
        float be = beta[ch] - m * ga;
        short4v sv = in4[i];
        short4v o;
        o.x = f2bf(fmaxf(fmaf(bf2f(sv.x), ga, be), 0.f));
        o.y = f2bf(fmaxf(fmaf(bf2f(sv.y), ga, be), 0.f));
        o.z = f2bf(fmaxf(fmaf(bf2f(sv.z), ga, be), 0.f));
        o.w = f2bf(fmaxf(fmaf(bf2f(sv.w), ga, be), 0.f));
        out4[i] = o;
    }
}

// ---------------------------------------------------------------------------
// K2: fused {depthwise 7x7 -> fdwt octet-major} AND {transpose hbf -> ht
// [B][HW][C]}. Blocks 0..255: dw7t. Blocks 256..511: trA (XCD-swizzled).
// ---------------------------------------------------------------------------
__global__ __launch_bounds__(256) void dw7t_tr_kernel(
    const short* __restrict__ in,   // hbf [B][C][HW]
    const float* __restrict__ dwk,  // [C][49]
    short* __restrict__ fdwt,       // [B][64][32][64][8]
    short* __restrict__ ht)         // [B][HW][C]
{
    __shared__ __align__(16) char smem[78112];
    int t = threadIdx.x;
    int blk = blockIdx.x;
    if (blk < 256) {
        short (*tile)[38][72] = (short(*)[38][72])smem;          // 43776 B
        float (*wk8)[49]      = (float(*)[49])(smem + 43776);    // 1568 B
        short (*outs)[2048]   = (short(*)[2048])(smem + 45344);  // 32768 B
        int b = blk >> 6, o8 = (blk >> 1) & 31, rh = blk & 1;
        int c0 = o8 * 8;
        unsigned* tz = (unsigned*)smem;
        for (int i = t; i < 10944; i += 256) tz[i] = 0u;         // zero tile
        for (int i = t; i < 392; i += 256)
            wk8[i / 49][i % 49] = dwk[(c0 + i / 49) * 49 + (i % 49)];
        __syncthreads();
        for (int ch = 0; ch < 8; ++ch) {
            const short* src = in + ((size_t)(b * C_ + c0 + ch)) * HW_;
            for (int i = t; i < 608; i += 256) {
                int rr = i >> 4, xq = i & 15;
                int ry = rh * 32 + rr - 3;
                if (ry >= 0 && ry < 64) {
                    short4v v = *(const short4v*)(src + ry * 64 + xq * 4);
                    *(short4v*)&tile[ch][rr][4 + xq * 4] = v;
                }
            }
        }
        __syncthreads();
        for (int it = 0; it < 16; ++it) {
            int q = it * 256 + t;
            int ch = q >> 9, y = (q >> 4) & 31, x0 = (q & 15) << 2;
            float a0 = 0.f, a1 = 0.f, a2 = 0.f, a3 = 0.f;
            const float* wr0 = wk8[ch];
            #pragma unroll
            for (int dy = 0; dy < 7; ++dy) {
                const short* trw = &tile[ch][y + dy][x0];
                short4v s0 = *(const short4v*)trw;
                short4v s1 = *(const short4v*)(trw + 4);
                short4v s2 = *(const short4v*)(trw + 8);
                float r[12] = {bf2f(s0.x), bf2f(s0.y), bf2f(s0.z), bf2f(s0.w),
                               bf2f(s1.x), bf2f(s1.y), bf2f(s1.z), bf2f(s1.w),
                               bf2f(s2.x), bf2f(s2.y), bf2f(s2.z), bf2f(s2.w)};
                const float* wr = wr0 + dy * 7;
                #pragma unroll
                for (int dx = 0; dx < 7; ++dx) {
                    float wv = wr[dx];
                    a0 = fmaf(r[dx + 1], wv, a0);
                    a1 = fmaf(r[dx + 2], wv, a1);
                    a2 = fmaf(r[dx + 3], wv, a2);
                    a3 = fmaf(r[dx + 4], wv, a3);
                }
            }
            short4v o;
            o.x = f2bf(a0); o.y = f2bf(a1); o.z = f2bf(a2); o.w = f2bf(a3);
            *(short4v*)&outs[ch][y * 64 + x0] = o;
        }
        __syncthreads();
        for (int it = 0; it < 8; ++it) {
            int p = it * 256 + t;
            short8 v;
            #pragma unroll
            for (int ch = 0; ch < 8; ++ch) v[ch] = outs[ch][p];
            *(short8*)(fdwt + (((size_t)(b * 64 + rh * 32 + (p >> 6)) * 32 + o8) * 64
                               + (p & 63)) * 8) = v;
        }
    } else {
        unsigned* ltile = (unsigned*)smem;     // 64*132 words = 33792 B
        int q0 = blk - 256;
        int q = ((q0 & 7) << 5) | (q0 >> 3);   // XCD swizzle (matches deform)
        int b = q >> 6;
        int px0 = (q & 63) * 64;
        const short* sb = in + (size_t)b * C_ * HW_;
        int pq4 = t & 15, cphi = t >> 4;
        #pragma unroll
        for (int i = 0; i < 8; ++i) {
            int cp = i * 16 + cphi;            // channel pair 0..127
            const short* r0 = sb + (size_t)(2 * cp) * HW_ + px0 + pq4 * 4;
            short4v lo = *(const short4v*)r0;
            short4v hi = *(const short4v*)(r0 + HW_);
            #pragma unroll
            for (int j = 0; j < 4; ++j) {
                int pl = pq4 * 4 + j;
                unsigned wrd = (unsigned)(unsigned short)lo[j]
                             | ((unsigned)(unsigned short)hi[j] << 16);
                ltile[pl * 132 + (cp ^ ((pl & 7) << 2))] = wrd;
            }
        }
        __syncthreads();
        int co = t & 31, ph2 = t >> 5;
        #pragma unroll
        for (int r = 0; r < 8; ++r) {
            int pl = r * 8 + ph2;
            uint4 v = *(const uint4*)&ltile[pl * 132 + ((co * 4) ^ ((pl & 7) << 2))];
            *(uint4*)(ht + ((size_t)b * HW_ + px0 + pl) * C_ + co * 8) = v;
        }
    }
}

// ---------------------------------------------------------------------------
// K3: pack weights. Coalesced fp32 reads, scattered 2B writes.
// ---------------------------------------------------------------------------
__global__ __launch_bounds__(256) void wpack_all_kernel(
    const float* __restrict__ w1, const float* __restrict__ w2,
    const float* __restrict__ pw1, const float* __restrict__ pw2,
    short* __restrict__ wp1, short* __restrict__ wp2,
    short* __restrict__ ppk1, short* __restrict__ ppk2)
{
    int blk = blockIdx.x;
    if (blk < 4608) {
        const float* w = (blk < 2304) ? w1 : w2;
        short* wp = (blk < 2304) ? wp1 : wp2;
        int src = (blk % 2304) * 256 + threadIdx.x;  // 0..589823, coalesced
        float v = w[src];
        int o = src / (C_ * KK_);                    // src = (o*C + c)*9 + g
        int r = src - o * (C_ * KK_);
        int c = r / KK_;
        int g = r - c * KK_;
        int ot   = o >> 5;
        int lane = (o & 31) | (((c >> 3) & 1) << 5);
        int j    = c & 7;
        int slab = g * 16 + (c >> 4);
        wp[(slab << 12) | (ot << 9) | (lane << 3) | j] = f2bf(v);
    } else {
        int q = blk - 4608;                          // 0..63
        const float* pw = (q < 32) ? pw1 : pw2;
        short* ppk = (q < 32) ? ppk1 : ppk2;
        int idx = (q & 31) * 256 + threadIdx.x;      // 0..8191
        int j = idx & 7, lane = (idx >> 3) & 63;
        int ot = (idx >> 9) & 1, sl = idx >> 10;     // 0..7
        int o = ot * 16 + (lane & 15);
        int k = sl * 32 + (lane >> 4) * 8 + j;
        ppk[idx] = (o < NOFF_) ? f2bf(pw[o * C_ + k]) : (short)0;
    }
}

// ---------------------------------------------------------------------------
// K4: fused deformable layer -- ROUND-3 structure verbatim (proven 44.5us
// floor after r4/r6/r10 overlap levers all lost to it). Octet fdwt stage A.
// NEW: when gstats != nullptr (layer 1), the epilogue also accumulates
// per-(b,group) sum/sumsq of y1 (pre-relu f32 values) via wave shuffle
// reduce + 64 atomicAdds -- this removes gn2's whole reduction pass.
// Stats regs live only in the epilogue (post register-pressure peak).
// ---------------------------------------------------------------------------
__global__ __launch_bounds__(1024, 4) void deform_fused_kernel(
    const short* __restrict__ ht,   const short* __restrict__ fdw,
    const short* __restrict__ ppk,  const float* __restrict__ pwb,
    const short* __restrict__ wp,   const float* __restrict__ bias,
    const float* __restrict__ resid, float* __restrict__ outf,
    short* __restrict__ outb,       float* __restrict__ gstats)
{
    int lb = ((blockIdx.x & 7) << 5) | (blockIdx.x >> 3);   // XCD swizzle
    int b = lb >> 6;
    int row = lb & 63;
    __shared__ int   i00[576], i01[576], i10[576], i11[576];
    __shared__ float c00[576], c01[576], c10[576], c11[576];
    __shared__ __align__(16) short sbuf[2][2][8192];  // [buf][panel][64px*128ch] = 64KB
    __shared__ float stat_lds[16][8];
    float* off_lds = (float*)&sbuf[0][0][0];          // 18*64 floats, dead before staging
    int t = threadIdx.x;
    int wv = t >> 6, lane = t & 63;
    int pq = lane >> 4, pr = lane & 15;
    int l31 = lane & 31, hi = lane >> 5;

    // ---- stage A: pw offsets via 16x16x32 MFMA (waves 0..7, full C) ----
    if (wv < 8) {
        int ot = wv & 1, ptw = wv >> 1;
        int px = ptw * 16 + pr;
        const short8* fdw8 = (const short8*)fdw;
        size_t fbase = ((size_t)(b * 64 + row)) * 32;
        const short8* ap = (const short8*)ppk;
        floatx4 pacc = (floatx4){0.f, 0.f, 0.f, 0.f};
        #pragma unroll
        for (int sl = 0; sl < 8; ++sl) {
            short8 af = ap[(sl * 2 + ot) * 64 + lane];
            short8 bf = fdw8[(fbase + sl * 4 + pq) * 64 + px];
            pacc = __builtin_amdgcn_mfma_f32_16x16x32_bf16(af, bf, pacc, 0, 0, 0);
        }
        #pragma unroll
        for (int r = 0; r < 4; ++r) {
            int o = ot * 16 + pq * 4 + r;
            if (o < NOFF_) off_lds[o * 64 + px] = pacc[r] + pwb[o];
        }
    }
    __syncthreads();

    // ---- stage B: bilinear coefficient tables ----
    if (t < 576) {
        int e = t;
        int k = e >> 6, p = e & 63;
        float offy = off_lds[(2 * k) * 64 + p];
        float offx = off_lds[(2 * k + 1) * 64 + p];
        float py = (float)row + (float)(k / 3 - 1) + offy;
        float px = (float)p   + (float)(k % 3 - 1) + offx;
        float y0f = floorf(py), x0f = floorf(px);
        float wy1 = py - y0f, wx1 = px - x0f;
        float wy0 = 1.f - wy1, wx0 = 1.f - wx1;
        float y1f = y0f + 1.f, x1f = x0f + 1.f;
        bool vy0 = (y0f >= 0.f) && (y0f <= 63.f);
        bool vy1 = (y1f >= 0.f) && (y1f <= 63.f);
        bool vx0 = (x0f >= 0.f) && (x0f <= 63.f);
        bool vx1 = (x1f >= 0.f) && (x1f <= 63.f);
        int iy0 = (int)fminf(fmaxf(y0f, 0.f), 63.f);
        int iy1 = (int)fminf(fmaxf(y1f, 0.f), 63.f);
        int ix0 = (int)fminf(fmaxf(x0f, 0.f), 63.f);
        int ix1 = (int)fminf(fmaxf(x1f, 0.f), 63.f);
        i00[e] = iy0 * 64 + ix0; i01[e] = iy0 * 64 + ix1;
        i10[e] = iy1 * 64 + ix0; i11[e] = iy1 * 64 + ix1;
        c00[e] = (vy0 && vx0) ? wy0 * wx0 : 0.f;
        c01[e] = (vy0 && vx1) ? wy0 * wx1 : 0.f;
        c10[e] = (vy1 && vx0) ? wy1 * wx0 : 0.f;
        c11[e] = (vy1 && vx1) ? wy1 * wx1 : 0.f;
    }
    __syncthreads();

    // ---- stage C: 9 taps, full C, double-buffered (round-3 proven) ----
    int c8a = t & 7;
    int pan = (t >> 3) & 1;
    int spx = t >> 4;                       // 0..63
    const short* hb0 = ht + ((size_t)b * HW_) * C_ + pan * 128 + c8a * 8;
    const short* hb1 = hb0 + 64;            // octet +8
    int slotA = (c8a ^ (spx & 15)) * 8;
    int slotB = ((c8a + 8) ^ (spx & 15)) * 8;
    int srow = spx * 128;

    short8 ra[4], rb[4];
    auto prefetch = [&](int g) {
        int e = g * 64 + spx;
        int a00 = i00[e], a01 = i01[e], a10 = i10[e], a11 = i11[e];
        ra[0] = *(const short8*)(hb0 + (size_t)a00 * C_);
        ra[1] = *(const short8*)(hb0 + (size_t)a01 * C_);
        ra[2] = *(const short8*)(hb0 + (size_t)a10 * C_);
        ra[3] = *(const short8*)(hb0 + (size_t)a11 * C_);
        rb[0] = *(const short8*)(hb1 + (size_t)a00 * C_);
        rb[1] = *(const short8*)(hb1 + (size_t)a01 * C_);
        rb[2] = *(const short8*)(hb1 + (size_t)a10 * C_);
        rb[3] = *(const short8*)(hb1 + (size_t)a11 * C_);
    };
    auto stage_write = [&](int g, int bi) {
        int e = g * 64 + spx;
        float w00 = c00[e], w01 = c01[e], w10 = c10[e], w11 = c11[e];
        uint4 va, vb;
        float f0, f1;
        #define BLEND(R, J) (w00 * bf2f(R[0][J]) + w01 * bf2f(R[1][J]) \
                           + w10 * bf2f(R[2][J]) + w11 * bf2f(R[3][J]))
        f0 = BLEND(ra, 0); f1 = BLEND(ra, 1); va.x = pkbf(f0, f1);
        f0 = BLEND(ra, 2); f1 = BLEND(ra, 3); va.y = pkbf(f0, f1);
        f0 = BLEND(ra, 4); f1 = BLEND(ra, 5); va.z = pkbf(f0, f1);
        f0 = BLEND(ra, 6); f1 = BLEND(ra, 7); va.w = pkbf(f0, f1);
        f0 = BLEND(rb, 0); f1 = BLEND(rb, 1); vb.x = pkbf(f0, f1);
        f0 = BLEND(rb, 2); f1 = BLEND(rb, 3); vb.y = pkbf(f0, f1);
        f0 = BLEND(rb, 4); f1 = BLEND(rb, 5); vb.z = pkbf(f0, f1);
        f0 = BLEND(rb, 6); f1 = BLEND(rb, 7); vb.w = pkbf(f0, f1);
        #undef BLEND
        short* sp = &sbuf[bi][pan][srow];
        *(uint4*)&sp[slotA] = va;
        *(uint4*)&sp[slotB] = vb;
    };

    // wave role: pairId = o-tile (32 rows), half = K-half (128 channels)
    int pairId = wv & 7;
    int half = wv >> 3;

    floatx16 acc[2];
    #pragma unroll
    for (int i = 0; i < 16; ++i) { acc[0][i] = 0.f; acc[1][i] = 0.f; }

    prefetch(0);
    stage_write(0, 0);
    prefetch(1);
    __syncthreads();

    const short8* wp8 = (const short8*)wp;
    int msk = l31 & 15;

    for (int g = 0; g < 9; ++g) {
        const short* sb = &sbuf[g & 1][half][0];
        #pragma unroll
        for (int q4 = 0; q4 < 2; ++q4) {
            short8 af[4];
            #pragma unroll
            for (int qq = 0; qq < 4; ++qq)
                af[qq] = wp8[(size_t)(((g * 16 + half * 8 + q4 * 4 + qq) * 8 + pairId) * 64 + lane)];
            #pragma unroll
            for (int qq = 0; qq < 4; ++qq) {
                int ksl = q4 * 4 + qq;                       // local slab 0..7
                int so = ((((ksl << 1) | hi) ^ msk) << 3);
                short8 b0 = *(const short8*)&sb[l31 * 128 + so];
                short8 b1 = *(const short8*)&sb[(32 + l31) * 128 + so];
                acc[0] = __builtin_amdgcn_mfma_f32_32x32x16_bf16(af[qq], b0, acc[0], 0, 0, 0);
                acc[1] = __builtin_amdgcn_mfma_f32_32x32x16_bf16(af[qq], b1, acc[1], 0, 0, 0);
            }
        }
        if (g + 1 < 9) {
            stage_write(g + 1, (g + 1) & 1);
            if (g + 2 < 9) prefetch(g + 2);
        }
        __syncthreads();
    }

    // ---- combine K-halves in LDS (lane-major planes, conflict-free) ----
    float* xch = (float*)&sbuf[0][0][0];     // 16 regions x 4KB = 64KB
    int wreg = (pairId * 2 + half) * 1024;   // floats
    floatx16 aw = half ? acc[0] : acc[1];
    floatx4* xq = (floatx4*)xch;
    #pragma unroll
    for (int j = 0; j < 4; ++j) {
        floatx4 v = {aw[j * 4 + 0], aw[j * 4 + 1], aw[j * 4 + 2], aw[j * 4 + 3]};
        xq[(wreg >> 2) + j * 64 + lane] = v;
    }
    __syncthreads();
    int rreg = (pairId * 2 + (half ^ 1)) * 1024;
    floatx16 ac = half ? acc[1] : acc[0];
    #pragma unroll
    for (int j = 0; j < 4; ++j) {
        floatx4 v = xq[(rreg >> 2) + j * 64 + lane];
        ac[j * 4 + 0] += v.x; ac[j * 4 + 1] += v.y;
        ac[j * 4 + 2] += v.z; ac[j * 4 + 3] += v.w;
    }

    // ---- epilogue: wave stores its px-tile (pxt = half); optional gn-stats
    // accumulation (j = r>>2 is compile-time under the unroll; group =
    // pairId*4 + j).
    float sj[4] = {0.f, 0.f, 0.f, 0.f};
    float qj[4] = {0.f, 0.f, 0.f, 0.f};
    #pragma unroll
    for (int r = 0; r < 16; ++r) {
        int o = pairId * 32 + (r & 3) + 8 * (r >> 2) + 4 * hi;
        float v = ac[r] + bias[o];
        size_t ob = ((size_t)(b * C_ + o)) * HW_ + row * 64 + half * 32 + l31;
        if (outf) {
            if (resid) v += resid[ob];
            outf[ob] = v;
        } else {
            outb[ob] = f2bf(v);
            sj[r >> 2] += v;
            qj[r >> 2] += v * v;
        }
    }
    if (gstats) {
        #pragma unroll
        for (int off = 32; off > 0; off >>= 1) {
            #pragma unroll
            for (int j = 0; j < 4; ++j) {
                sj[j] += __shfl_down(sj[j], off, 64);
                qj[j] += __shfl_down(qj[j], off, 64);
            }
        }
        if (lane == 0) {
            #pragma unroll
            for (int j = 0; j < 4; ++j) {
                stat_lds[wv][j] = sj[j];
                stat_lds[wv][4 + j] = qj[j];
            }
        }
        __syncthreads();
        if (t < 32) {
            int pid = t >> 2, j = t & 3;
            float sT = stat_lds[pid][j] + stat_lds[pid + 8][j];
            float qT = stat_lds[pid][4 + j] + stat_lds[pid + 8][4 + j];
            int idx = b * 32 + pid * 4 + j;
            atomicAdd(&gstats[idx], sT);
            atomicAdd(&gstats[128 + idx], qT);
        }
    }
}

// ---------------------------------------------------------------------------
extern "C" void kernel_launch(void* const* d_in, const int* in_sizes, int n_in,
                              void* d_out, int out_size, void* d_ws, size_t ws_size,
                              hipStream_t stream)
{
    const float* x     = (const float*)d_in[0];
    const float* gn1_g = (const float*)d_in[1];
    const float* gn1_b = (const float*)d_in[2];
    const float* dw1   = (const float*)d_in[3];
    const float* pw1   = (const float*)d_in[4];
    const float* pwb1  = (const float*)d_in[5];
    const float* w1    = (const float*)d_in[6];
    const float* b1    = (const float*)d_in[7];
    const float* gn2_g = (const float*)d_in[8];
    const float* gn2_b = (const float*)d_in[9];
    const float* dw2   = (const float*)d_in[10];
    const float* pw2   = (const float*)d_in[11];
    const float* pwb2  = (const float*)d_in[12];
    const float* w2    = (const float*)d_in[13];
    const float* b2    = (const float*)d_in[14];
    float* out = (float*)d_out;

    float* ws   = (float*)d_ws;
    short* y1b  = (short*)ws;                  // bf16 [B][C][HW]       (8 MB)
    short* hbf  = (short*)(ws + 2097152);      // bf16 [B][C][HW]       (8 MB)
    short* hbt  = (short*)(ws + 4194304);      // bf16 [B][HW][C]       (8 MB)
    short* fdwt = (short*)(ws + 8388608);      // bf16 [B][64][32][64][8] (8 MB)
    short* wp1  = (short*)(ws + 10485760);     // 589,824 bf16
    short* wp2  = (short*)(ws + 10780672);     // 589,824 bf16
    short* ppk1 = (short*)(ws + 11075584);     // 8,192 bf16
    short* ppk2 = (short*)(ws + 11079680);     // 8,192 bf16
    float* gstats = ws + 11083776;             // 256 floats (sum | sumsq)

    wpack_all_kernel<<<4672, 256, 0, stream>>>(w1, w2, pw1, pw2,
                                               wp1, wp2, ppk1, ppk2);
    hipMemsetAsync(gstats, 0, 256 * sizeof(float), stream);

    // layer 1 (deform-1 epilogue accumulates gn2 stats)
    gn_relu_f32_kernel<<<B_ * NG_, 1024, 0, stream>>>(x, gn1_g, gn1_b, hbf);
    dw7t_tr_kernel<<<512, 256, 0, stream>>>(hbf, dw1, fdwt, hbt);
    deform_fused_kernel<<<B_ * H_, 1024, 0, stream>>>(
        hbt, fdwt, ppk1, pwb1, wp1, b1, nullptr, nullptr, y1b, gstats);

    // layer 2 (+ residual x); gn2 is a pure apply pass (stats precomputed)
    gn_apply_bf16_kernel<<<512, 1024, 0, stream>>>(y1b, gstats, gn2_g, gn2_b, hbf);
    dw7t_tr_kernel<<<512, 256, 0, stream>>>(hbf, dw2, fdwt, hbt);
    deform_fused_kernel<<<B_ * H_, 1024, 0, stream>>>(
        hbt, fdwt, ppk2, pwb2, wp2, b2, x, out, nullptr, nullptr);
}

// Round 12
// 236.783 us; speedup vs baseline: 1.1705x; 1.0253x over previous
//
#include <hip/hip_runtime.h>

#define B_    4
#define C_    256
#define H_    64
#define W_    64
#define HW_   4096
#define NG_   32
#define CPG_  8
#define KK_   9
#define NOFF_ 18

typedef __attribute__((ext_vector_type(8))) short short8;
typedef __attribute__((ext_vector_type(4))) short short4v;
typedef __attribute__((ext_vector_type(4))) float floatx4;
typedef __attribute__((ext_vector_type(16))) float floatx16;

static __device__ __forceinline__ short f2bf(float f) {
    union { float f; unsigned u; } v; v.f = f;
    unsigned r = v.u + 0x7fff + ((v.u >> 16) & 1);   // RNE
    return (short)(r >> 16);
}
static __device__ __forceinline__ float bf2f(short s) {
    union { unsigned u; float f; } v;
    v.u = ((unsigned)(unsigned short)s) << 16;
    return v.f;
}
// packed f32x2 -> bf16x2 (RNE), single VALU op
static __device__ __forceinline__ unsigned pkbf(float lo, float hi) {
    unsigned r;
    asm("v_cvt_pk_bf16_f32 %0, %1, %2" : "=v"(r) : "v"(lo), "v"(hi));
    return r;
}

// ---------------------------------------------------------------------------
// K1: GroupNorm (32 groups) + ReLU -> bf16 [C][HW]. fp32-input, LDS-cached
// (r11-proven): the (b,group) slab (128 KB) stays in LDS so the normalize
// pass does not re-read global.
// ---------------------------------------------------------------------------
__global__ __launch_bounds__(1024) void gn_relu_f32_kernel(
    const float* __restrict__ in, const float* __restrict__ gamma,
    const float* __restrict__ beta, short* __restrict__ outb)
{
    __shared__ float cache[32768];         // 128 KB
    __shared__ float red[32];
    __shared__ float sh_rs, sh_m;
    int b = blockIdx.x >> 5;
    int g = blockIdx.x & 31;
    const int N = CPG_ * HW_;              // 32768
    size_t base = ((size_t)(b * C_ + g * CPG_)) * HW_;
    const float4* in4 = (const float4*)(in + base);
    int t = threadIdx.x;

    float s = 0.f, ss = 0.f;
    for (int i = t; i < N / 4; i += 1024) {
        float4 v = in4[i];
        *(float4*)&cache[i * 4] = v;
        s  += v.x + v.y + v.z + v.w;
        ss += v.x * v.x + v.y * v.y + v.z * v.z + v.w * v.w;
    }
    #pragma unroll
    for (int off = 32; off > 0; off >>= 1) {
        s  += __shfl_down(s, off, 64);
        ss += __shfl_down(ss, off, 64);
    }
    int wid = t >> 6;
    if ((t & 63) == 0) { red[wid] = s; red[16 + wid] = ss; }
    __syncthreads();
    if (t == 0) {
        float S = 0.f, SS = 0.f;
        #pragma unroll
        for (int i = 0; i < 16; ++i) { S += red[i]; SS += red[16 + i]; }
        float m = S / (float)N;
        float var = SS / (float)N - m * m;
        sh_rs = rsqrtf(var + 1e-5f);
        sh_m = m;
    }
    __syncthreads();
    float rs = sh_rs, m = sh_m;
    short4v* out4 = (short4v*)(outb + base);
    for (int i = t; i < N / 4; i += 1024) {
        int ch = g * CPG_ + (i >> 10);
        float ga = gamma[ch] * rs;
        float be = beta[ch] - m * ga;
        float4 v = *(const float4*)&cache[i * 4];
        short4v o;
        o.x = f2bf(fmaxf(fmaf(v.x, ga, be), 0.f));
        o.y = f2bf(fmaxf(fmaf(v.y, ga, be), 0.f));
        o.z = f2bf(fmaxf(fmaf(v.z, ga, be), 0.f));
        o.w = f2bf(fmaxf(fmaf(v.w, ga, be), 0.f));
        out4[i] = o;
    }
}

// ---------------------------------------------------------------------------
// K2: fused {depthwise 7x7 -> fdwt octet-major} AND {transpose -> ht
// [B][HW][C]}. Blocks 0..255: dw7t. Blocks 256..511: trA (XCD-swizzled).
// Round-12: optional fused GroupNorm-apply on the INPUT (layer 2): when
// pstats != nullptr, each block reduces deform-1's per-row group partials
// (64 x {sum,sumsq}) and applies relu(ga*v+be) on load. This replaces the
// standalone gn_apply kernel and its hbf round-trip.
// ---------------------------------------------------------------------------
__global__ __launch_bounds__(256) void dw7t_tr_kernel(
    const short* __restrict__ in,   // layer1: hbf; layer2: y1b  [B][C][HW]
    const float* __restrict__ dwk,  // [C][49]
    short* __restrict__ fdwt,       // [B][64][32][64][8]
    short* __restrict__ ht,         // [B][HW][C]
    const float* __restrict__ pstats,  // [B][64][32][2] or nullptr
    const float* __restrict__ gamma, const float* __restrict__ beta)
{
    __shared__ __align__(16) char smem[78144];
    const float Ninv = 1.f / (float)(CPG_ * HW_);
    int t = threadIdx.x;
    int blk = blockIdx.x;
    if (blk < 256) {
        short (*tile)[38][72] = (short(*)[38][72])smem;          // 43776 B
        float (*wk8)[49]      = (float(*)[49])(smem + 43776);    // 1568 B
        short (*outs)[2048]   = (short(*)[2048])(smem + 45344);  // 32768 B
        float* gsh            = (float*)(smem + 78112);          // 2 floats
        int b = blk >> 6, o8 = (blk >> 1) & 31, rh = blk & 1;
        int c0 = o8 * 8;
        // ---- group stats for this block's single group (o8) ----
        if (pstats && t < 64) {
            const float* pp = pstats + (((size_t)(b * 64 + t)) * 32 + o8) * 2;
            float s = pp[0], q = pp[1];
            #pragma unroll
            for (int off = 32; off > 0; off >>= 1) {
                s += __shfl_down(s, off, 64);
                q += __shfl_down(q, off, 64);
            }
            if (t == 0) {
                float m = s * Ninv;
                float var = q * Ninv - m * m;
                gsh[0] = m;
                gsh[1] = rsqrtf(var + 1e-5f);
            }
        }
        unsigned* tz = (unsigned*)smem;
        for (int i = t; i < 10944; i += 256) tz[i] = 0u;         // zero tile
        for (int i = t; i < 392; i += 256)
            wk8[i / 49][i % 49] = dwk[(c0 + i / 49) * 49 + (i % 49)];
        __syncthreads();
        float m_g = 0.f, rs_g = 0.f;
        if (pstats) { m_g = gsh[0]; rs_g = gsh[1]; }
        // load 8 planes, rows rh*32-3 .. rh*32+34 (halo), cols at +4 pad
        for (int ch = 0; ch < 8; ++ch) {
            const short* src = in + ((size_t)(b * C_ + c0 + ch)) * HW_;
            float ga = 0.f, be = 0.f;
            if (pstats) {
                ga = gamma[c0 + ch] * rs_g;
                be = beta[c0 + ch] - m_g * ga;
            }
            for (int i = t; i < 608; i += 256) {
                int rr = i >> 4, xq = i & 15;
                int ry = rh * 32 + rr - 3;
                if (ry >= 0 && ry < 64) {
                    short4v v = *(const short4v*)(src + ry * 64 + xq * 4);
                    if (pstats) {
                        v.x = f2bf(fmaxf(fmaf(bf2f(v.x), ga, be), 0.f));
                        v.y = f2bf(fmaxf(fmaf(bf2f(v.y), ga, be), 0.f));
                        v.z = f2bf(fmaxf(fmaf(bf2f(v.z), ga, be), 0.f));
                        v.w = f2bf(fmaxf(fmaf(bf2f(v.w), ga, be), 0.f));
                    }
                    *(short4v*)&tile[ch][rr][4 + xq * 4] = v;
                }
            }
        }
        __syncthreads();
        // compute: 4096 quads (ch,y,x0)
        for (int it = 0; it < 16; ++it) {
            int q = it * 256 + t;
            int ch = q >> 9, y = (q >> 4) & 31, x0 = (q & 15) << 2;
            float a0 = 0.f, a1 = 0.f, a2 = 0.f, a3 = 0.f;
            const float* wr0 = wk8[ch];
            #pragma unroll
            for (int dy = 0; dy < 7; ++dy) {
                const short* trw = &tile[ch][y + dy][x0];
                short4v s0 = *(const short4v*)trw;
                short4v s1 = *(const short4v*)(trw + 4);
                short4v s2 = *(const short4v*)(trw + 8);
                float r[12] = {bf2f(s0.x), bf2f(s0.y), bf2f(s0.z), bf2f(s0.w),
                               bf2f(s1.x), bf2f(s1.y), bf2f(s1.z), bf2f(s1.w),
                               bf2f(s2.x), bf2f(s2.y), bf2f(s2.z), bf2f(s2.w)};
                const float* wr = wr0 + dy * 7;
                #pragma unroll
                for (int dx = 0; dx < 7; ++dx) {
                    float wv = wr[dx];
                    a0 = fmaf(r[dx + 1], wv, a0);
                    a1 = fmaf(r[dx + 2], wv, a1);
                    a2 = fmaf(r[dx + 3], wv, a2);
                    a3 = fmaf(r[dx + 4], wv, a3);
                }
            }
            short4v o;
            o.x = f2bf(a0); o.y = f2bf(a1); o.z = f2bf(a2); o.w = f2bf(a3);
            *(short4v*)&outs[ch][y * 64 + x0] = o;
        }
        __syncthreads();
        // octet-major coalesced write: 2048 px-chunks of 16B
        for (int it = 0; it < 8; ++it) {
            int p = it * 256 + t;
            short8 v;
            #pragma unroll
            for (int ch = 0; ch < 8; ++ch) v[ch] = outs[ch][p];
            *(short8*)(fdwt + (((size_t)(b * 64 + rh * 32 + (p >> 6)) * 32 + o8) * 64
                               + (p & 63)) * 8) = v;
        }
    } else {
        unsigned* ltile = (unsigned*)smem;     // 64*132 words = 33792 B
        float* gmrs = (float*)(smem + 65536);  // 64 floats (m | rs)
        int q0 = blk - 256;
        int q = ((q0 & 7) << 5) | (q0 >> 3);   // XCD swizzle (matches deform)
        int b = q >> 6;
        int px0 = (q & 63) * 64;
        const short* sb = in + (size_t)b * C_ * HW_;
        // ---- per-group stats for all 32 groups (8 threads per group) ----
        if (pstats) {
            int gq = t >> 3, rq = t & 7;
            float s = 0.f, qs = 0.f;
            for (int rr = rq; rr < 64; rr += 8) {
                const float* pp = pstats + (((size_t)(b * 64 + rr)) * 32 + gq) * 2;
                s += pp[0]; qs += pp[1];
            }
            s  += __shfl_down(s, 4, 64);  qs += __shfl_down(qs, 4, 64);
            s  += __shfl_down(s, 2, 64);  qs += __shfl_down(qs, 2, 64);
            s  += __shfl_down(s, 1, 64);  qs += __shfl_down(qs, 1, 64);
            if (rq == 0) {
                float m = s * Ninv;
                float var = qs * Ninv - m * m;
                gmrs[gq] = m;
                gmrs[32 + gq] = rsqrtf(var + 1e-5f);
            }
        }
        __syncthreads();
        int pq4 = t & 15, cphi = t >> 4;
        #pragma unroll
        for (int i = 0; i < 8; ++i) {
            int cp = i * 16 + cphi;            // channel pair 0..127
            const short* r0 = sb + (size_t)(2 * cp) * HW_ + px0 + pq4 * 4;
            short4v lo = *(const short4v*)r0;
            short4v hi = *(const short4v*)(r0 + HW_);
            float ga0 = 0.f, be0 = 0.f, ga1 = 0.f, be1 = 0.f;
            if (pstats) {
                int g0 = cp >> 2;
                float mm = gmrs[g0], rr2 = gmrs[32 + g0];
                ga0 = gamma[2 * cp] * rr2;     be0 = beta[2 * cp] - mm * ga0;
                ga1 = gamma[2 * cp + 1] * rr2; be1 = beta[2 * cp + 1] - mm * ga1;
            }
            #pragma unroll
            for (int j = 0; j < 4; ++j) {
                int pl = pq4 * 4 + j;
                unsigned wrd;
                if (pstats) {
                    float v0 = fmaxf(fmaf(bf2f(lo[j]), ga0, be0), 0.f);
                    float v1 = fmaxf(fmaf(bf2f(hi[j]), ga1, be1), 0.f);
                    wrd = pkbf(v0, v1);
                } else {
                    wrd = (unsigned)(unsigned short)lo[j]
                        | ((unsigned)(unsigned short)hi[j] << 16);
                }
                ltile[pl * 132 + (cp ^ ((pl & 7) << 2))] = wrd;
            }
        }
        __syncthreads();
        int co = t & 31, ph2 = t >> 5;
        #pragma unroll
        for (int r = 0; r < 8; ++r) {
            int pl = r * 8 + ph2;
            uint4 v = *(const uint4*)&ltile[pl * 132 + ((co * 4) ^ ((pl & 7) << 2))];
            *(uint4*)(ht + ((size_t)b * HW_ + px0 + pl) * C_ + co * 8) = v;
        }
    }
}

// ---------------------------------------------------------------------------
// K3: pack weights. Coalesced fp32 reads, scattered 2B writes.
// ---------------------------------------------------------------------------
__global__ __launch_bounds__(256) void wpack_all_kernel(
    const float* __restrict__ w1, const float* __restrict__ w2,
    const float* __restrict__ pw1, const float* __restrict__ pw2,
    short* __restrict__ wp1, short* __restrict__ wp2,
    short* __restrict__ ppk1, short* __restrict__ ppk2)
{
    int blk = blockIdx.x;
    if (blk < 4608) {
        const float* w = (blk < 2304) ? w1 : w2;
        short* wp = (blk < 2304) ? wp1 : wp2;
        int src = (blk % 2304) * 256 + threadIdx.x;  // 0..589823, coalesced
        float v = w[src];
        int o = src / (C_ * KK_);                    // src = (o*C + c)*9 + g
        int r = src - o * (C_ * KK_);
        int c = r / KK_;
        int g = r - c * KK_;
        int ot   = o >> 5;
        int lane = (o & 31) | (((c >> 3) & 1) << 5);
        int j    = c & 7;
        int slab = g * 16 + (c >> 4);
        wp[(slab << 12) | (ot << 9) | (lane << 3) | j] = f2bf(v);
    } else {
        int q = blk - 4608;                          // 0..63
        const float* pw = (q < 32) ? pw1 : pw2;
        short* ppk = (q < 32) ? ppk1 : ppk2;
        int idx = (q & 31) * 256 + threadIdx.x;      // 0..8191
        int j = idx & 7, lane = (idx >> 3) & 63;
        int ot = (idx >> 9) & 1, sl = idx >> 10;     // 0..7
        int o = ot * 16 + (lane & 15);
        int k = sl * 32 + (lane >> 4) * 8 + j;
        ppk[idx] = (o < NOFF_) ? f2bf(pw[o * C_ + k]) : (short)0;
    }
}

// ---------------------------------------------------------------------------
// K4: fused deformable layer -- round-3 structure (proven floor). When
// pstats != nullptr (layer 1), the epilogue also writes this block's
// per-(b,row) group partial sums NON-atomically (one 64B store/block --
// r11's 16K contended atomicAdds cost ~5us of kernel-exit tail).
// ---------------------------------------------------------------------------
__global__ __launch_bounds__(1024, 4) void deform_fused_kernel(
    const short* __restrict__ ht,   const short* __restrict__ fdw,
    const short* __restrict__ ppk,  const float* __restrict__ pwb,
    const short* __restrict__ wp,   const float* __restrict__ bias,
    const float* __restrict__ resid, float* __restrict__ outf,
    short* __restrict__ outb,       float* __restrict__ pstats)
{
    int lb = ((blockIdx.x & 7) << 5) | (blockIdx.x >> 3);   // XCD swizzle
    int b = lb >> 6;
    int row = lb & 63;
    __shared__ int   i00[576], i01[576], i10[576], i11[576];
    __shared__ float c00[576], c01[576], c10[576], c11[576];
    __shared__ __align__(16) short sbuf[2][2][8192];  // [buf][panel][64px*128ch] = 64KB
    __shared__ float stat_lds[16][8];
    float* off_lds = (float*)&sbuf[0][0][0];          // 18*64 floats, dead before staging
    int t = threadIdx.x;
    int wv = t >> 6, lane = t & 63;
    int pq = lane >> 4, pr = lane & 15;
    int l31 = lane & 31, hi = lane >> 5;

    // ---- stage A: pw offsets via 16x16x32 MFMA (waves 0..7, full C) ----
    if (wv < 8) {
        int ot = wv & 1, ptw = wv >> 1;
        int px = ptw * 16 + pr;
        const short8* fdw8 = (const short8*)fdw;
        size_t fbase = ((size_t)(b * 64 + row)) * 32;
        const short8* ap = (const short8*)ppk;
        floatx4 pacc = (floatx4){0.f, 0.f, 0.f, 0.f};
        #pragma unroll
        for (int sl = 0; sl < 8; ++sl) {
            short8 af = ap[(sl * 2 + ot) * 64 + lane];
            short8 bf = fdw8[(fbase + sl * 4 + pq) * 64 + px];
            pacc = __builtin_amdgcn_mfma_f32_16x16x32_bf16(af, bf, pacc, 0, 0, 0);
        }
        #pragma unroll
        for (int r = 0; r < 4; ++r) {
            int o = ot * 16 + pq * 4 + r;
            if (o < NOFF_) off_lds[o * 64 + px] = pacc[r] + pwb[o];
        }
    }
    __syncthreads();

    // ---- stage B: bilinear coefficient tables ----
    if (t < 576) {
        int e = t;
        int k = e >> 6, p = e & 63;
        float offy = off_lds[(2 * k) * 64 + p];
        float offx = off_lds[(2 * k + 1) * 64 + p];
        float py = (float)row + (float)(k / 3 - 1) + offy;
        float px = (float)p   + (float)(k % 3 - 1) + offx;
        float y0f = floorf(py), x0f = floorf(px);
        float wy1 = py - y0f, wx1 = px - x0f;
        float wy0 = 1.f - wy1, wx0 = 1.f - wx1;
        float y1f = y0f + 1.f, x1f = x0f + 1.f;
        bool vy0 = (y0f >= 0.f) && (y0f <= 63.f);
        bool vy1 = (y1f >= 0.f) && (y1f <= 63.f);
        bool vx0 = (x0f >= 0.f) && (x0f <= 63.f);
        bool vx1 = (x1f >= 0.f) && (x1f <= 63.f);
        int iy0 = (int)fminf(fmaxf(y0f, 0.f), 63.f);
        int iy1 = (int)fminf(fmaxf(y1f, 0.f), 63.f);
        int ix0 = (int)fminf(fmaxf(x0f, 0.f), 63.f);
        int ix1 = (int)fminf(fmaxf(x1f, 0.f), 63.f);
        i00[e] = iy0 * 64 + ix0; i01[e] = iy0 * 64 + ix1;
        i10[e] = iy1 * 64 + ix0; i11[e] = iy1 * 64 + ix1;
        c00[e] = (vy0 && vx0) ? wy0 * wx0 : 0.f;
        c01[e] = (vy0 && vx1) ? wy0 * wx1 : 0.f;
        c10[e] = (vy1 && vx0) ? wy1 * wx0 : 0.f;
        c11[e] = (vy1 && vx1) ? wy1 * wx1 : 0.f;
    }
    __syncthreads();

    // ---- stage C: 9 taps, full C, double-buffered (round-3 proven) ----
    int c8a = t & 7;
    int pan = (t >> 3) & 1;
    int spx = t >> 4;                       // 0..63
    const short* hb0 = ht + ((size_t)b * HW_) * C_ + pan * 128 + c8a * 8;
    const short* hb1 = hb0 + 64;            // octet +8
    int slotA = (c8a ^ (spx & 15)) * 8;
    int slotB = ((c8a + 8) ^ (spx & 15)) * 8;
    int srow = spx * 128;

    short8 ra[4], rb[4];
    auto prefetch = [&](int g) {
        int e = g * 64 + spx;
        int a00 = i00[e], a01 = i01[e], a10 = i10[e], a11 = i11[e];
        ra[0] = *(const short8*)(hb0 + (size_t)a00 * C_);
        ra[1] = *(const short8*)(hb0 + (size_t)a01 * C_);
        ra[2] = *(const short8*)(hb0 + (size_t)a10 * C_);
        ra[3] = *(const short8*)(hb0 + (size_t)a11 * C_);
        rb[0] = *(const short8*)(hb1 + (size_t)a00 * C_);
        rb[1] = *(const short8*)(hb1 + (size_t)a01 * C_);
        rb[2] = *(const short8*)(hb1 + (size_t)a10 * C_);
        rb[3] = *(const short8*)(hb1 + (size_t)a11 * C_);
    };
    auto stage_write = [&](int g, int bi) {
        int e = g * 64 + spx;
        float w00 = c00[e], w01 = c01[e], w10 = c10[e], w11 = c11[e];
        uint4 va, vb;
        float f0, f1;
        #define BLEND(R, J) (w00 * bf2f(R[0][J]) + w01 * bf2f(R[1][J]) \
                           + w10 * bf2f(R[2][J]) + w11 * bf2f(R[3][J]))
        f0 = BLEND(ra, 0); f1 = BLEND(ra, 1); va.x = pkbf(f0, f1);
        f0 = BLEND(ra, 2); f1 = BLEND(ra, 3); va.y = pkbf(f0, f1);
        f0 = BLEND(ra, 4); f1 = BLEND(ra, 5); va.z = pkbf(f0, f1);
        f0 = BLEND(ra, 6); f1 = BLEND(ra, 7); va.w = pkbf(f0, f1);
        f0 = BLEND(rb, 0); f1 = BLEND(rb, 1); vb.x = pkbf(f0, f1);
        f0 = BLEND(rb, 2); f1 = BLEND(rb, 3); vb.y = pkbf(f0, f1);
        f0 = BLEND(rb, 4); f1 = BLEND(rb, 5); vb.z = pkbf(f0, f1);
        f0 = BLEND(rb, 6); f1 = BLEND(rb, 7); vb.w = pkbf(f0, f1);
        #undef BLEND
        short* sp = &sbuf[bi][pan][srow];
        *(uint4*)&sp[slotA] = va;
        *(uint4*)&sp[slotB] = vb;
    };

    // wave role: pairId = o-tile (32 rows), half = K-half (128 channels)
    int pairId = wv & 7;
    int half = wv >> 3;

    floatx16 acc[2];
    #pragma unroll
    for (int i = 0; i < 16; ++i) { acc[0][i] = 0.f; acc[1][i] = 0.f; }

    prefetch(0);
    stage_write(0, 0);
    prefetch(1);
    __syncthreads();

    const short8* wp8 = (const short8*)wp;
    int msk = l31 & 15;

    for (int g = 0; g < 9; ++g) {
        const short* sb = &sbuf[g & 1][half][0];
        #pragma unroll
        for (int q4 = 0; q4 < 2; ++q4) {
            short8 af[4];
            #pragma unroll
            for (int qq = 0; qq < 4; ++qq)
                af[qq] = wp8[(size_t)(((g * 16 + half * 8 + q4 * 4 + qq) * 8 + pairId) * 64 + lane)];
            #pragma unroll
            for (int qq = 0; qq < 4; ++qq) {
                int ksl = q4 * 4 + qq;                       // local slab 0..7
                int so = ((((ksl << 1) | hi) ^ msk) << 3);
                short8 b0 = *(const short8*)&sb[l31 * 128 + so];
                short8 b1 = *(const short8*)&sb[(32 + l31) * 128 + so];
                acc[0] = __builtin_amdgcn_mfma_f32_32x32x16_bf16(af[qq], b0, acc[0], 0, 0, 0);
                acc[1] = __builtin_amdgcn_mfma_f32_32x32x16_bf16(af[qq], b1, acc[1], 0, 0, 0);
            }
        }
        if (g + 1 < 9) {
            stage_write(g + 1, (g + 1) & 1);
            if (g + 2 < 9) prefetch(g + 2);
        }
        __syncthreads();
    }

    // ---- combine K-halves in LDS (lane-major planes, conflict-free) ----
    float* xch = (float*)&sbuf[0][0][0];     // 16 regions x 4KB = 64KB
    int wreg = (pairId * 2 + half) * 1024;   // floats
    floatx16 aw = half ? acc[0] : acc[1];
    floatx4* xq = (floatx4*)xch;
    #pragma unroll
    for (int j = 0; j < 4; ++j) {
        floatx4 v = {aw[j * 4 + 0], aw[j * 4 + 1], aw[j * 4 + 2], aw[j * 4 + 3]};
        xq[(wreg >> 2) + j * 64 + lane] = v;
    }
    __syncthreads();
    int rreg = (pairId * 2 + (half ^ 1)) * 1024;
    floatx16 ac = half ? acc[1] : acc[0];
    #pragma unroll
    for (int j = 0; j < 4; ++j) {
        floatx4 v = xq[(rreg >> 2) + j * 64 + lane];
        ac[j * 4 + 0] += v.x; ac[j * 4 + 1] += v.y;
        ac[j * 4 + 2] += v.z; ac[j * 4 + 3] += v.w;
    }

    // ---- epilogue: store px-tile; optional gn-stats partials (group =
    // pairId*4 + (r>>2), compile-time under the unroll).
    float sj[4] = {0.f, 0.f, 0.f, 0.f};
    float qj[4] = {0.f, 0.f, 0.f, 0.f};
    #pragma unroll
    for (int r = 0; r < 16; ++r) {
        int o = pairId * 32 + (r & 3) + 8 * (r >> 2) + 4 * hi;
        float v = ac[r] + bias[o];
        size_t ob = ((size_t)(b * C_ + o)) * HW_ + row * 64 + half * 32 + l31;
        if (outf) {
            if (resid) v += resid[ob];
            outf[ob] = v;
        } else {
            outb[ob] = f2bf(v);
            sj[r >> 2] += v;
            qj[r >> 2] += v * v;
        }
    }
    if (pstats) {
        #pragma unroll
        for (int off = 32; off > 0; off >>= 1) {
            #pragma unroll
            for (int j = 0; j < 4; ++j) {
                sj[j] += __shfl_down(sj[j], off, 64);
                qj[j] += __shfl_down(qj[j], off, 64);
            }
        }
        if (lane == 0) {
            #pragma unroll
            for (int j = 0; j < 4; ++j) {
                stat_lds[wv][j] = sj[j];
                stat_lds[wv][4 + j] = qj[j];
            }
        }
        __syncthreads();
        if (t < 32) {
            int pid = t >> 2, j = t & 3;
            float sT = stat_lds[pid][j] + stat_lds[pid + 8][j];
            float qT = stat_lds[pid][4 + j] + stat_lds[pid + 8][4 + j];
            float* pp = pstats + (((size_t)(b * 64 + row)) * 32 + pid * 4 + j) * 2;
            pp[0] = sT;
            pp[1] = qT;
        }
    }
}

// ---------------------------------------------------------------------------
extern "C" void kernel_launch(void* const* d_in, const int* in_sizes, int n_in,
                              void* d_out, int out_size, void* d_ws, size_t ws_size,
                              hipStream_t stream)
{
    const float* x     = (const float*)d_in[0];
    const float* gn1_g = (const float*)d_in[1];
    const float* gn1_b = (const float*)d_in[2];
    const float* dw1   = (const float*)d_in[3];
    const float* pw1   = (const float*)d_in[4];
    const float* pwb1  = (const float*)d_in[5];
    const float* w1    = (const float*)d_in[6];
    const float* b1    = (const float*)d_in[7];
    const float* gn2_g = (const float*)d_in[8];
    const float* gn2_b = (const float*)d_in[9];
    const float* dw2   = (const float*)d_in[10];
    const float* pw2   = (const float*)d_in[11];
    const float* pwb2  = (const float*)d_in[12];
    const float* w2    = (const float*)d_in[13];
    const float* b2    = (const float*)d_in[14];
    float* out = (float*)d_out;

    float* ws   = (float*)d_ws;
    short* y1b  = (short*)ws;                  // bf16 [B][C][HW]       (8 MB)
    short* hbf  = (short*)(ws + 2097152);      // bf16 [B][C][HW]       (8 MB)
    short* hbt  = (short*)(ws + 4194304);      // bf16 [B][HW][C]       (8 MB)
    short* fdwt = (short*)(ws + 8388608);      // bf16 [B][64][32][64][8] (8 MB)
    short* wp1  = (short*)(ws + 10485760);     // 589,824 bf16
    short* wp2  = (short*)(ws + 10780672);     // 589,824 bf16
    short* ppk1 = (short*)(ws + 11075584);     // 8,192 bf16
    short* ppk2 = (short*)(ws + 11079680);     // 8,192 bf16
    float* pstats = ws + 11083776;             // [B][64][32][2] = 16384 floats

    wpack_all_kernel<<<4672, 256, 0, stream>>>(w1, w2, pw1, pw2,
                                               wp1, wp2, ppk1, ppk2);

    // layer 1 (deform-1 epilogue writes per-row gn2 stat partials)
    gn_relu_f32_kernel<<<B_ * NG_, 1024, 0, stream>>>(x, gn1_g, gn1_b, hbf);
    dw7t_tr_kernel<<<512, 256, 0, stream>>>(hbf, dw1, fdwt, hbt,
                                            nullptr, nullptr, nullptr);
    deform_fused_kernel<<<B_ * H_, 1024, 0, stream>>>(
        hbt, fdwt, ppk1, pwb1, wp1, b1, nullptr, nullptr, y1b, pstats);

    // layer 2 (+ residual x): gn2 apply is fused into dw7t_tr's loads
    dw7t_tr_kernel<<<512, 256, 0, stream>>>(y1b, dw2, fdwt, hbt,
                                            pstats, gn2_g, gn2_b);
    deform_fused_kernel<<<B_ * H_, 1024, 0, stream>>>(
        hbt, fdwt, ppk2, pwb2, wp2, b2, x, out, nullptr, nullptr);
}